// Round 2
// baseline (1034.597 us; speedup 1.0000x reference)
//
#include <hip/hip_runtime.h>
#include <cmath>

#define NNODE 40000
#define NREL  2000
#define NTRI  600000
#define DIMK  128
#define F3    384
#define NPROX 64
#define EPSN  1e-12f
#define NSLICE 8
#define SLICE_ROWS (NNODE / NSLICE)

typedef unsigned short ushort_t;
typedef __attribute__((ext_vector_type(8))) short bf16x8;
typedef __attribute__((ext_vector_type(4))) float f32x4;

static __device__ __forceinline__ float waveSum(float v) {
#pragma unroll
    for (int m = 32; m >= 1; m >>= 1) v += __shfl_xor(v, m, 64);
    return v;
}

static __device__ __forceinline__ float bf2f(ushort_t h) {
    return __uint_as_float(((unsigned int)h) << 16);
}

static __device__ __forceinline__ void qreduce4(float4& v) {
#pragma unroll
    for (int m = 16; m <= 32; m <<= 1) {
        v.x += __shfl_xor(v.x, m, 64);
        v.y += __shfl_xor(v.y, m, 64);
        v.z += __shfl_xor(v.z, m, 64);
        v.w += __shfl_xor(v.w, m, 64);
    }
}

// ---------------- CSR build ----------------
__global__ void k_count3(const int* __restrict__ rA, const int* __restrict__ rE,
                         const int* __restrict__ rR, int* __restrict__ dA,
                         int* __restrict__ dE, int* __restrict__ dR) {
    int t = blockIdx.x * 256 + threadIdx.x;
    if (t < NTRI) {
        atomicAdd(&dA[rA[t]], 1);
        atomicAdd(&dE[rE[t]], 1);
        atomicAdd(&dR[rR[t]], 1);
    }
}

__global__ void k_scan_fast(const int* __restrict__ dA, int* __restrict__ oA,
                            const int* __restrict__ dE, int* __restrict__ oE,
                            const int* __restrict__ dR, int* __restrict__ oR) {
    const int* deg = blockIdx.x == 0 ? dA : (blockIdx.x == 1 ? dE : dR);
    int* off = blockIdx.x == 0 ? oA : (blockIdx.x == 1 ? oE : oR);
    __shared__ int wsum[16];
    __shared__ int wpre[16];
    int tid = threadIdx.x;
    int lane = tid & 63, wv = tid >> 6;
    const int CH = 40;
    int base = tid * CH;
    int s = 0;
    for (int i = 0; i < CH; i++) {
        int idx = base + i;
        s += (idx < NNODE) ? deg[idx] : 0;
    }
    int incl = s;
#pragma unroll
    for (int m = 1; m < 64; m <<= 1) {
        int v = __shfl_up(incl, m, 64);
        if (lane >= m) incl += v;
    }
    if (lane == 63) wsum[wv] = incl;
    __syncthreads();
    if (tid < 16) {
        int v = wsum[tid];
#pragma unroll
        for (int m = 1; m < 16; m <<= 1) {
            int u = __shfl_up(v, m, 64);
            if (tid >= m) v += u;
        }
        wpre[tid] = v;
    }
    __syncthreads();
    int waveoff = (wv == 0) ? 0 : wpre[wv - 1];
    int run = waveoff + incl - s;
    for (int i = 0; i < CH; i++) {
        int idx = base + i;
        if (idx < NNODE) {
            off[idx] = run;
            run += deg[idx];
        }
    }
    if (tid == 0) off[NNODE] = wpre[15];
}

// XCD-sliced payload placement: slice = blockIdx&7 (round-robin XCD heuristic).
__global__ __launch_bounds__(256) void k_place_sliced(
    const int* __restrict__ rA, const int* __restrict__ cA,
    const int* __restrict__ rE, const int* __restrict__ cE,
    const int* __restrict__ rR, const int* __restrict__ cR,
    const int* __restrict__ ridx, const float* __restrict__ rval,
    const float* __restrict__ nrm,
    const int* __restrict__ oA, const int* __restrict__ oE, const int* __restrict__ oR,
    int* __restrict__ cntA, int* __restrict__ cntE, int* __restrict__ cntR,
    int2* __restrict__ ePackSc, int* __restrict__ eColE, int* __restrict__ eColR) {
    int slice = blockIdx.x & (NSLICE - 1);
    int t = (blockIdx.x >> 3) * 256 + threadIdx.x;
    if (t >= NTRI) return;
    int lo = slice * SLICE_ROWS;
    int r = rA[t];
    if ((unsigned)(r - lo) < (unsigned)SLICE_ROWS) {
        int rid = ridx[t];
        float v = rval[t];
        float sc = v / fmaxf(fabsf(v) * nrm[rid], EPSN);
        int p = oA[r] + atomicAdd(&cntA[r], 1);
        ePackSc[p] = make_int2(cA[t] | (rid << 16), __float_as_int(sc));
    }
    r = rE[t];
    if ((unsigned)(r - lo) < (unsigned)SLICE_ROWS)
        eColE[oE[r] + atomicAdd(&cntE[r], 1)] = cE[t];
    r = rR[t];
    if ((unsigned)(r - lo) < (unsigned)SLICE_ROWS)
        eColR[oR[r] + atomicAdd(&cntR[r], 1)] = cR[t];
}

// ---------------- small precomputes ----------------
__global__ void k_relprep(const float* __restrict__ rel_emb,
                          const float* __restrict__ e_attn, const float* __restrict__ r_attn,
                          float* __restrict__ nrm, float2* __restrict__ attL0,
                          float2* __restrict__ attL1) {
    int r = blockIdx.x;
    int lane = threadIdx.x;
    float a = rel_emb[r * DIMK + lane];
    float b = rel_emb[r * DIMK + 64 + lane];
    float nn = waveSum(a * a + b * b);
    float d0 = waveSum(a * e_attn[lane] + b * e_attn[64 + lane]);
    float d1 = waveSum(a * e_attn[DIMK + lane] + b * e_attn[DIMK + 64 + lane]);
    float d2 = waveSum(a * r_attn[lane] + b * r_attn[64 + lane]);
    float d3 = waveSum(a * r_attn[DIMK + lane] + b * r_attn[DIMK + 64 + lane]);
    if (lane == 0) {
        nrm[r] = sqrtf(nn);
        attL0[r] = make_float2(d0, d2);
        attL1[r] = make_float2(d1, d3);
    }
}

// both encoders' proxy prep in one dispatch
__global__ void k_proxyprep2(const float* __restrict__ e_proxy, const float* __restrict__ r_proxy,
                             float* __restrict__ pnT_e, float* __restrict__ pnT_r) {
    int enc = blockIdx.x >= NPROX;
    int k = blockIdx.x & (NPROX - 1);
    const float* proxy = enc ? r_proxy : e_proxy;
    float* pnT = enc ? pnT_r : pnT_e;
    int lane = threadIdx.x;
    float v[6];
    float ss = 0.f;
#pragma unroll
    for (int j = 0; j < 6; j++) {
        v[j] = proxy[k * F3 + j * 64 + lane];
        ss += v[j] * v[j];
    }
    ss = waveSum(ss);
    float inv = 1.0f / fmaxf(sqrtf(ss), EPSN);
#pragma unroll
    for (int j = 0; j < 6; j++) pnT[(j * 64 + lane) * NPROX + k] = v[j] * inv;
}

// both encoders' gate prep in one dispatch
__global__ void k_gateprep2(const float* __restrict__ e_gate, const float* __restrict__ r_gate,
                            ushort_t* __restrict__ the, ushort_t* __restrict__ tle,
                            ushort_t* __restrict__ thr, ushort_t* __restrict__ tlr) {
    int enc = blockIdx.x >= F3;
    int k = enc ? blockIdx.x - F3 : blockIdx.x;
    const float* g = enc ? r_gate : e_gate;
    ushort_t* th = enc ? thr : the;
    ushort_t* tl = enc ? tlr : tle;
    int c = threadIdx.x;
    float v = g[(size_t)k * F3 + c];
    unsigned int b = __float_as_uint(v);
    th[(size_t)c * F3 + k] = (ushort_t)(b >> 16);
    float lo = v - __uint_as_float(b & 0xffff0000u);
    tl[(size_t)c * F3 + k] = (ushort_t)(__float_as_uint(lo) >> 16);
}

// ---------------- fused neighbor mean + tanh ----------------
__global__ __launch_bounds__(256) void k_avg2(
    const int* __restrict__ offE, const int* __restrict__ eColE, const float* __restrict__ ent_emb,
    const int* __restrict__ offR, const int* __restrict__ eColR, const float* __restrict__ rel_emb,
    float* __restrict__ out_e, float* __restrict__ out_r) {
    int gw = (blockIdx.x * blockDim.x + threadIdx.x) >> 6;
    int lane = threadIdx.x & 63;
    if (gw >= 2 * NNODE) return;
    bool isR = gw >= NNODE;
    int wid = isR ? gw - NNODE : gw;
    const int* off = isR ? offR : offE;
    const int* ecol = isR ? eColR : eColE;
    const float4* emb4 = (const float4*)(isR ? rel_emb : ent_emb);
    float* outp = isR ? out_r : out_e;
    int q = lane >> 4, ql = lane & 15;
    int e0 = off[wid], e1 = off[wid + 1];
    float4 aA = {0, 0, 0, 0}, aB = {0, 0, 0, 0};
    for (int base = e0; base < e1; base += 64) {
        int n = min(64, e1 - base);
        int mc = (lane < n) ? ecol[base + lane] : -1;
        for (int j = 0; j < n; j += 4) {
            int e = j + q;
            int c = __shfl(mc, e, 64);
            if (e < n) {
                float4 va = emb4[(size_t)c * 32 + ql];
                float4 vb = emb4[(size_t)c * 32 + 16 + ql];
                aA.x += va.x; aA.y += va.y; aA.z += va.z; aA.w += va.w;
                aB.x += vb.x; aB.y += vb.y; aB.z += vb.z; aB.w += vb.w;
            }
        }
    }
    qreduce4(aA);
    qreduce4(aB);
    if (q == 0) {
        float invd = (e1 > e0) ? 1.0f / (float)(e1 - e0) : 0.0f;
        float4* o = (float4*)outp;
        float4 ra = {tanhf(aA.x * invd), tanhf(aA.y * invd), tanhf(aA.z * invd), tanhf(aA.w * invd)};
        float4 rb = {tanhf(aB.x * invd), tanhf(aB.y * invd), tanhf(aB.z * invd), tanhf(aB.w * invd)};
        o[(size_t)wid * 96 + ql] = ra;
        o[(size_t)wid * 96 + 16 + ql] = rb;
    }
}

// ---------------- fused reflection attention aggregation ----------------
__global__ __launch_bounds__(256) void k_agg2(
    const int* __restrict__ off, const int2* __restrict__ ePackSc,
    const float2* __restrict__ attL, const float* __restrict__ rel_emb,
    float* __restrict__ out_e, float* __restrict__ out_r, int lin) {
    int wid = (blockIdx.x * blockDim.x + threadIdx.x) >> 6;
    int lane = threadIdx.x & 63;
    if (wid >= NNODE) return;
    int q = lane >> 4, ql = lane & 15;
    int e0 = off[wid], e1 = off[wid + 1];
    const float4* rel4 = (const float4*)rel_emb;
    const float4* pe4 = (const float4*)out_e;
    const float4* pr4 = (const float4*)out_r;
    int sA = lin * 32 + ql, sB = lin * 32 + 16 + ql;
    float4 aEa = {0, 0, 0, 0}, aEb = {0, 0, 0, 0}, aRa = {0, 0, 0, 0}, aRb = {0, 0, 0, 0};
    float sE = 0.f, sR = 0.f;
    for (int base = e0; base < e1; base += 64) {
        int n = min(64, e1 - base);
        int pk = 0;
        float sc = 0.f, wE = 0.f, wR = 0.f;
        if (lane < n) {
            int2 ps = ePackSc[base + lane];
            pk = ps.x;
            sc = __int_as_float(ps.y);
            float2 a = attL[pk >> 16];
            wE = __expf(sc * a.x);
            wR = __expf(sc * a.y);
        }
        for (int j = 0; j < n; j += 4) {
            int e = j + q;
            int pke = __shfl(pk, e, 64);
            float sce = __shfl(sc, e, 64);
            float wEe = __shfl(wE, e, 64);
            float wRe = __shfl(wR, e, 64);
            int c = pke & 0xFFFF;
            int r = pke >> 16;
            float4 ra = rel4[(size_t)r * 32 + ql];
            float4 rb = rel4[(size_t)r * 32 + 16 + ql];
            float4 fa = pe4[(size_t)c * 96 + sA];
            float4 fb = pe4[(size_t)c * 96 + sB];
            float4 ga = pr4[(size_t)c * 96 + sA];
            float4 gb = pr4[(size_t)c * 96 + sB];
            float tax = sce * ra.x, tay = sce * ra.y, taz = sce * ra.z, taw = sce * ra.w;
            float tbx = sce * rb.x, tby = sce * rb.y, tbz = sce * rb.z, tbw = sce * rb.w;
            float dE = fa.x * tax + fa.y * tay + fa.z * taz + fa.w * taw +
                       fb.x * tbx + fb.y * tby + fb.z * tbz + fb.w * tbw;
            float dR = ga.x * tax + ga.y * tay + ga.z * taz + ga.w * taw +
                       gb.x * tbx + gb.y * tby + gb.z * tbz + gb.w * tbw;
#pragma unroll
            for (int m = 1; m <= 8; m <<= 1) {
                dE += __shfl_xor(dE, m, 64);
                dR += __shfl_xor(dR, m, 64);
            }
            dE *= 2.f;
            dR *= 2.f;
            aEa.x += wEe * (fa.x - dE * tax);
            aEa.y += wEe * (fa.y - dE * tay);
            aEa.z += wEe * (fa.z - dE * taz);
            aEa.w += wEe * (fa.w - dE * taw);
            aEb.x += wEe * (fb.x - dE * tbx);
            aEb.y += wEe * (fb.y - dE * tby);
            aEb.z += wEe * (fb.z - dE * tbz);
            aEb.w += wEe * (fb.w - dE * tbw);
            aRa.x += wRe * (ga.x - dR * tax);
            aRa.y += wRe * (ga.y - dR * tay);
            aRa.z += wRe * (ga.z - dR * taz);
            aRa.w += wRe * (ga.w - dR * taw);
            aRb.x += wRe * (gb.x - dR * tbx);
            aRb.y += wRe * (gb.y - dR * tby);
            aRb.z += wRe * (gb.z - dR * tbz);
            aRb.w += wRe * (gb.w - dR * tbw);
            sE += wEe;
            sR += wRe;
        }
    }
    qreduce4(aEa);
    qreduce4(aEb);
    qreduce4(aRa);
    qreduce4(aRb);
#pragma unroll
    for (int m = 16; m <= 32; m <<= 1) {
        sE += __shfl_xor(sE, m, 64);
        sR += __shfl_xor(sR, m, 64);
    }
    if (q == 0) {
        float iE = (e1 > e0) ? 1.f / sE : 0.f;
        float4* o = (float4*)out_e;
        float4 wa = {tanhf(aEa.x * iE), tanhf(aEa.y * iE), tanhf(aEa.z * iE), tanhf(aEa.w * iE)};
        float4 wb = {tanhf(aEb.x * iE), tanhf(aEb.y * iE), tanhf(aEb.z * iE), tanhf(aEb.w * iE)};
        o[(size_t)wid * 96 + (lin + 1) * 32 + ql] = wa;
        o[(size_t)wid * 96 + (lin + 1) * 32 + 16 + ql] = wb;
    } else if (q == 1) {
        float iR = (e1 > e0) ? 1.f / sR : 0.f;
        float4* o = (float4*)out_r;
        float4 wa = {tanhf(aRa.x * iR), tanhf(aRa.y * iR), tanhf(aRa.z * iR), tanhf(aRa.w * iR)};
        float4 wb = {tanhf(aRb.x * iR), tanhf(aRb.y * iR), tanhf(aRb.z * iR), tanhf(aRb.w * iR)};
        o[(size_t)wid * 96 + (lin + 1) * 32 + ql] = wa;
        o[(size_t)wid * 96 + (lin + 1) * 32 + 16 + ql] = wb;
    }
}

// ---------------- epilogue (z = encoder) ----------------
__global__ void k_scores(const float* __restrict__ out_e, const float* __restrict__ out_r,
                         const float* __restrict__ pnT_e, const float* __restrict__ pnT_r,
                         float* __restrict__ pa_e, float* __restrict__ pa_r) {
    const float* outb = blockIdx.z ? out_r : out_e;
    const float* pnT = blockIdx.z ? pnT_r : pnT_e;
    float* pa = blockIdx.z ? pa_r : pa_e;
    __shared__ __align__(16) float As[16][68];
    __shared__ __align__(16) float Bs[16][68];
    __shared__ float Ss[64][65];
    __shared__ float rnS[64];
    int tid = threadIdx.x;
    int row0 = blockIdx.x * 64;
    int kk = tid & 15, rr = tid >> 4;
    int cb = tid & 63, kb = tid >> 6;
    int tx = tid & 15, ty = tid >> 4;
    int c0 = tx * 4, r0 = ty * 4;
    float acc[4][4] = {};
    float ssp[4] = {};
    for (int k0 = 0; k0 < F3; k0 += 16) {
#pragma unroll
        for (int u = 0; u < 4; u++) {
            int r = rr + u * 16;
            float v = outb[(size_t)(row0 + r) * F3 + k0 + kk];
            As[kk][r] = v;
            ssp[u] += v * v;
        }
#pragma unroll
        for (int u = 0; u < 4; u++) {
            int k = kb + u * 4;
            Bs[k][cb] = pnT[(size_t)(k0 + k) * NPROX + cb];
        }
        __syncthreads();
#pragma unroll
        for (int k = 0; k < 16; k++) {
            float4 av = *(const float4*)&As[k][r0];
            float4 bv = *(const float4*)&Bs[k][c0];
            float a[4] = {av.x, av.y, av.z, av.w};
            float b[4] = {bv.x, bv.y, bv.z, bv.w};
#pragma unroll
            for (int i = 0; i < 4; i++)
#pragma unroll
                for (int j = 0; j < 4; j++) acc[i][j] += a[i] * b[j];
        }
        __syncthreads();
    }
#pragma unroll
    for (int u = 0; u < 4; u++) {
        float ss = ssp[u];
#pragma unroll
        for (int m = 1; m < 16; m <<= 1) ss += __shfl_xor(ss, m, 64);
        if (kk == 0) rnS[rr + u * 16] = 1.0f / fmaxf(sqrtf(ss), EPSN);
    }
    __syncthreads();
#pragma unroll
    for (int i = 0; i < 4; i++) {
        float rn = rnS[r0 + i];
#pragma unroll
        for (int j = 0; j < 4; j++) Ss[r0 + i][c0 + j] = acc[i][j] * rn;
    }
    __syncthreads();
    if (tid < 64) {
        int r = tid;
        float m = -1e30f;
        for (int c = 0; c < 64; c++) m = fmaxf(m, Ss[r][c]);
        float s = 0.f;
        for (int c = 0; c < 64; c++) s += expf(Ss[r][c] - m);
        float inv = 1.f / s;
        float* po = pa + (size_t)(row0 + r) * NPROX;
        for (int c = 0; c < 64; c++) po[c] = expf(Ss[r][c] - m) * inv;
    }
}

__global__ void k_pf(const float* __restrict__ pa_e, const float* __restrict__ pa_r,
                     const float* __restrict__ e_proxy, const float* __restrict__ r_proxy,
                     const float* __restrict__ out_e, const float* __restrict__ out_r,
                     ushort_t* __restrict__ pfh_e, ushort_t* __restrict__ pfl_e,
                     ushort_t* __restrict__ pfh_r, ushort_t* __restrict__ pfl_r) {
    const float* pa = blockIdx.z ? pa_r : pa_e;
    const float* proxy = blockIdx.z ? r_proxy : e_proxy;
    const float* outb = blockIdx.z ? out_r : out_e;
    ushort_t* pfh = blockIdx.z ? pfh_r : pfh_e;
    ushort_t* pfl = blockIdx.z ? pfl_r : pfl_e;
    __shared__ __align__(16) float As[16][68];
    __shared__ __align__(16) float Bs[16][68];
    int tid = threadIdx.x;
    int row0 = blockIdx.x * 64;
    int col0 = blockIdx.y * 64;
    int kk = tid & 15, rr = tid >> 4;
    int cb = tid & 63, kb = tid >> 6;
    int tx = tid & 15, ty = tid >> 4;
    int c0 = tx * 4, r0 = ty * 4;
    float acc[4][4] = {};
    for (int k0 = 0; k0 < NPROX; k0 += 16) {
#pragma unroll
        for (int u = 0; u < 4; u++) {
            int r = rr + u * 16;
            As[kk][r] = pa[(size_t)(row0 + r) * NPROX + k0 + kk];
        }
#pragma unroll
        for (int u = 0; u < 4; u++) {
            int k = kb + u * 4;
            Bs[k][cb] = proxy[(size_t)(k0 + k) * F3 + col0 + cb];
        }
        __syncthreads();
#pragma unroll
        for (int k = 0; k < 16; k++) {
            float4 av = *(const float4*)&As[k][r0];
            float4 bv = *(const float4*)&Bs[k][c0];
            float a[4] = {av.x, av.y, av.z, av.w};
            float b[4] = {bv.x, bv.y, bv.z, bv.w};
#pragma unroll
            for (int i = 0; i < 4; i++)
#pragma unroll
                for (int j = 0; j < 4; j++) acc[i][j] += a[i] * b[j];
        }
        __syncthreads();
    }
#pragma unroll
    for (int i = 0; i < 4; i++)
#pragma unroll
        for (int j = 0; j < 4; j++) {
            size_t idx = (size_t)(row0 + r0 + i) * F3 + col0 + c0 + j;
            float v = outb[idx] - acc[i][j];
            unsigned int b = __float_as_uint(v);
            pfh[idx] = (ushort_t)(b >> 16);
            float lo = v - __uint_as_float(b & 0xffff0000u);
            pfl[idx] = (ushort_t)(__float_as_uint(lo) >> 16);
        }
}

// Barrier-free gate GEMM: A fragments read directly from global (L2/L3-resident
// pfh/pfl, 61 MB total), no LDS staging, no __syncthreads in the K-loop.
// Rationale (R1 counters): MfmaUtil 13.5%, VALUBusy 16%, HBM 25% -> stall-bound
// on the 2-barriers-per-k-step LDS staging; LDS shared A across only 2 waves.
__global__ __launch_bounds__(256) void k_gate_mfma(
    const ushort_t* __restrict__ pfh_e, const ushort_t* __restrict__ pfl_e,
    const ushort_t* __restrict__ pfh_r, const ushort_t* __restrict__ pfl_r,
    const ushort_t* __restrict__ gTh_e, const ushort_t* __restrict__ gTl_e,
    const ushort_t* __restrict__ gTh_r, const ushort_t* __restrict__ gTl_r,
    const float* __restrict__ e_bias, const float* __restrict__ r_bias,
    const float* __restrict__ out_e, const float* __restrict__ out_r,
    float* __restrict__ dout) {
    const ushort_t* pfh = blockIdx.z ? pfh_r : pfh_e;
    const ushort_t* pfl = blockIdx.z ? pfl_r : pfl_e;
    const ushort_t* gTh = blockIdx.z ? gTh_r : gTh_e;
    const ushort_t* gTl = blockIdx.z ? gTl_r : gTl_e;
    const float* bias = blockIdx.z ? r_bias : e_bias;
    const float* outb = blockIdx.z ? out_r : out_e;
    int outoff = blockIdx.z ? F3 : 0;
    int tid = threadIdx.x;
    int w = tid >> 6, lane = tid & 63;
    int quad = lane >> 4, l16 = lane & 15;
    int wrow = (w >> 1) * 64, wcol = (w & 1) * 64;
    int gr0 = blockIdx.x * 128;
    int cb0 = blockIdx.y * 128;
    f32x4 acc[4][4];
#pragma unroll
    for (int rt = 0; rt < 4; rt++)
#pragma unroll
        for (int ct = 0; ct < 4; ct++) acc[rt][ct] = (f32x4){0.f, 0.f, 0.f, 0.f};

    const bf16x8 zz = (bf16x8){0, 0, 0, 0, 0, 0, 0, 0};
    for (int k0 = 0; k0 < F3; k0 += 32) {
        bf16x8 ah[4], al[4], bh[4], bl[4];
#pragma unroll
        for (int rt = 0; rt < 4; rt++) {
            int ar = gr0 + wrow + rt * 16 + l16;
            if (ar < NNODE) {
                ah[rt] = *(const bf16x8*)&pfh[(size_t)ar * F3 + k0 + quad * 8];
                al[rt] = *(const bf16x8*)&pfl[(size_t)ar * F3 + k0 + quad * 8];
            } else {
                ah[rt] = zz;
                al[rt] = zz;
            }
        }
#pragma unroll
        for (int ct = 0; ct < 4; ct++) {
            int bc = cb0 + wcol + ct * 16 + l16;
            bh[ct] = *(const bf16x8*)&gTh[(size_t)bc * F3 + k0 + quad * 8];
            bl[ct] = *(const bf16x8*)&gTl[(size_t)bc * F3 + k0 + quad * 8];
        }
#pragma unroll
        for (int rt = 0; rt < 4; rt++)
#pragma unroll
            for (int ct = 0; ct < 4; ct++) {
                acc[rt][ct] = __builtin_amdgcn_mfma_f32_16x16x32_bf16(ah[rt], bh[ct], acc[rt][ct], 0, 0, 0);
                acc[rt][ct] = __builtin_amdgcn_mfma_f32_16x16x32_bf16(ah[rt], bl[ct], acc[rt][ct], 0, 0, 0);
                acc[rt][ct] = __builtin_amdgcn_mfma_f32_16x16x32_bf16(al[rt], bh[ct], acc[rt][ct], 0, 0, 0);
            }
    }
#pragma unroll
    for (int rt = 0; rt < 4; rt++) {
        int rbase = gr0 + wrow + rt * 16 + quad * 4;
#pragma unroll
        for (int reg = 0; reg < 4; reg++) {
            int row = rbase + reg;
            if (row >= NNODE) continue;
#pragma unroll
            for (int ct = 0; ct < 4; ct++) {
                int c = cb0 + wcol + ct * 16 + l16;
                float x = acc[rt][ct][reg] + bias[c];
                float g = 1.f / (1.f + __expf(-x));
                size_t idx = (size_t)row * F3 + c;
                float pf = bf2f(pfh[idx]) + bf2f(pfl[idx]);
                float o = outb[idx];
                dout[(size_t)row * 768 + outoff + c] = g * o + (1.f - g) * pf;
            }
        }
    }
}

// ---------------- launch ----------------
extern "C" void kernel_launch(void* const* d_in, const int* in_sizes, int n_in,
                              void* d_out, int out_size, void* d_ws, size_t ws_size,
                              hipStream_t stream) {
    const int* ent_adj = (const int*)d_in[0];
    const int* rel_adj = (const int*)d_in[1];
    const int* adj_list = (const int*)d_in[4];
    const int* r_index = (const int*)d_in[5];
    const float* r_val = (const float*)d_in[6];
    const float* ent_emb = (const float*)d_in[9];
    const float* rel_emb = (const float*)d_in[10];
    const float* e_attn = (const float*)d_in[11];
    const float* e_gate = (const float*)d_in[12];
    const float* e_proxy = (const float*)d_in[13];
    const float* e_bias = (const float*)d_in[14];
    const float* r_attn = (const float*)d_in[15];
    const float* r_gate = (const float*)d_in[16];
    const float* r_proxy = (const float*)d_in[17];
    const float* r_bias = (const float*)d_in[18];
    float* out = (float*)d_out;

    char* ws = (char*)d_ws;
    size_t off = 0;
    auto alloc = [&](size_t bytes) -> void* {
        off = (off + 255) & ~(size_t)255;
        void* p = ws + off;
        off += bytes;
        return p;
    };

    int* degcur = (int*)alloc(6 * NNODE * sizeof(int));
    int* degA = degcur, *curA = degcur + NNODE;
    int* degE = degcur + 2 * NNODE, *curE = degcur + 3 * NNODE;
    int* degR = degcur + 4 * NNODE, *curR = degcur + 5 * NNODE;
    int* offA = (int*)alloc((NNODE + 1) * sizeof(int));
    int* offE = (int*)alloc((NNODE + 1) * sizeof(int));
    int* offR = (int*)alloc((NNODE + 1) * sizeof(int));
    int2* ePackSc = (int2*)alloc(NTRI * sizeof(int2));
    int* eColE = (int*)alloc(NTRI * sizeof(int));
    int* eColR = (int*)alloc(NTRI * sizeof(int));
    float* nrm = (float*)alloc(NREL * sizeof(float));
    float2* attL0 = (float2*)alloc(NREL * sizeof(float2));
    float2* attL1 = (float2*)alloc(NREL * sizeof(float2));
    float* pnT_e = (float*)alloc((size_t)F3 * NPROX * sizeof(float));
    float* pnT_r = (float*)alloc((size_t)F3 * NPROX * sizeof(float));
    ushort_t* gTh_e = (ushort_t*)alloc((size_t)F3 * F3 * sizeof(ushort_t));
    ushort_t* gTl_e = (ushort_t*)alloc((size_t)F3 * F3 * sizeof(ushort_t));
    ushort_t* gTh_r = (ushort_t*)alloc((size_t)F3 * F3 * sizeof(ushort_t));
    ushort_t* gTl_r = (ushort_t*)alloc((size_t)F3 * F3 * sizeof(ushort_t));
    float* pa_e = (float*)alloc((size_t)NNODE * NPROX * sizeof(float));
    float* pa_r = (float*)alloc((size_t)NNODE * NPROX * sizeof(float));
    ushort_t* pfh_e = (ushort_t*)alloc((size_t)NNODE * F3 * sizeof(ushort_t));
    ushort_t* pfl_e = (ushort_t*)alloc((size_t)NNODE * F3 * sizeof(ushort_t));
    ushort_t* pfh_r = (ushort_t*)alloc((size_t)NNODE * F3 * sizeof(ushort_t));
    ushort_t* pfl_r = (ushort_t*)alloc((size_t)NNODE * F3 * sizeof(ushort_t));
    float* out_e = (float*)alloc((size_t)NNODE * F3 * sizeof(float));
    float* out_r = (float*)alloc((size_t)NNODE * F3 * sizeof(float));
    (void)ws_size; (void)in_sizes; (void)n_in; (void)out_size;

    hipMemsetAsync(degcur, 0, 6 * NNODE * sizeof(int), stream);

    int gT = (NTRI + 255) / 256;
    k_count3<<<gT, 256, 0, stream>>>(adj_list, ent_adj, rel_adj, degA, degE, degR);
    k_scan_fast<<<3, 1024, 0, stream>>>(degA, offA, degE, offE, degR, offR);
    k_relprep<<<NREL, 64, 0, stream>>>(rel_emb, e_attn, r_attn, nrm, attL0, attL1);
    k_place_sliced<<<gT * NSLICE, 256, 0, stream>>>(
        adj_list, adj_list + NTRI, ent_adj, ent_adj + NTRI, rel_adj, rel_adj + NTRI,
        r_index + NTRI, r_val, nrm, offA, offE, offR, curA, curE, curR,
        ePackSc, eColE, eColR);
    k_proxyprep2<<<2 * NPROX, 64, 0, stream>>>(e_proxy, r_proxy, pnT_e, pnT_r);
    k_gateprep2<<<2 * F3, F3, 0, stream>>>(e_gate, r_gate, gTh_e, gTl_e, gTh_r, gTl_r);

    k_avg2<<<(2 * NNODE) / 4, 256, 0, stream>>>(offE, eColE, ent_emb, offR, eColR, rel_emb,
                                                out_e, out_r);

    int gW = NNODE / 4;
    k_agg2<<<gW, 256, 0, stream>>>(offA, ePackSc, attL0, rel_emb, out_e, out_r, 0);
    k_agg2<<<gW, 256, 0, stream>>>(offA, ePackSc, attL1, rel_emb, out_e, out_r, 1);

    dim3 gS(NNODE / 64, 1, 2);
    dim3 gP(NNODE / 64, F3 / 64, 2);
    dim3 gG((NNODE + 127) / 128, F3 / 128, 2);
    k_scores<<<gS, 256, 0, stream>>>(out_e, out_r, pnT_e, pnT_r, pa_e, pa_r);
    k_pf<<<gP, 256, 0, stream>>>(pa_e, pa_r, e_proxy, r_proxy, out_e, out_r,
                                 pfh_e, pfl_e, pfh_r, pfl_r);
    k_gate_mfma<<<gG, 256, 0, stream>>>(pfh_e, pfl_e, pfh_r, pfl_r, gTh_e, gTl_e, gTh_r, gTl_r,
                                        e_bias, r_bias, out_e, out_r, out);
}

// Round 3
// 993.790 us; speedup vs baseline: 1.0411x; 1.0411x over previous
//
#include <hip/hip_runtime.h>
#include <cmath>

#define NNODE 40000
#define NREL  2000
#define NTRI  600000
#define DIMK  128
#define F3    384
#define NPROX 64
#define EPSN  1e-12f
#define NSLICE 8
#define SLICE_ROWS (NNODE / NSLICE)

typedef unsigned short ushort_t;
typedef __attribute__((ext_vector_type(8))) short bf16x8;
typedef __attribute__((ext_vector_type(4))) float f32x4;

static __device__ __forceinline__ float waveSum(float v) {
#pragma unroll
    for (int m = 32; m >= 1; m >>= 1) v += __shfl_xor(v, m, 64);
    return v;
}

static __device__ __forceinline__ float bf2f(ushort_t h) {
    return __uint_as_float(((unsigned int)h) << 16);
}

static __device__ __forceinline__ void qreduce4(float4& v) {
#pragma unroll
    for (int m = 16; m <= 32; m <<= 1) {
        v.x += __shfl_xor(v.x, m, 64);
        v.y += __shfl_xor(v.y, m, 64);
        v.z += __shfl_xor(v.z, m, 64);
        v.w += __shfl_xor(v.w, m, 64);
    }
}

// ---------------- CSR build ----------------
__global__ void k_count3(const int* __restrict__ rA, const int* __restrict__ rE,
                         const int* __restrict__ rR, int* __restrict__ dA,
                         int* __restrict__ dE, int* __restrict__ dR) {
    int t = blockIdx.x * 256 + threadIdx.x;
    if (t < NTRI) {
        atomicAdd(&dA[rA[t]], 1);
        atomicAdd(&dE[rE[t]], 1);
        atomicAdd(&dR[rR[t]], 1);
    }
}

__global__ void k_scan_fast(const int* __restrict__ dA, int* __restrict__ oA,
                            const int* __restrict__ dE, int* __restrict__ oE,
                            const int* __restrict__ dR, int* __restrict__ oR) {
    const int* deg = blockIdx.x == 0 ? dA : (blockIdx.x == 1 ? dE : dR);
    int* off = blockIdx.x == 0 ? oA : (blockIdx.x == 1 ? oE : oR);
    __shared__ int wsum[16];
    __shared__ int wpre[16];
    int tid = threadIdx.x;
    int lane = tid & 63, wv = tid >> 6;
    const int CH = 40;
    int base = tid * CH;
    int s = 0;
    for (int i = 0; i < CH; i++) {
        int idx = base + i;
        s += (idx < NNODE) ? deg[idx] : 0;
    }
    int incl = s;
#pragma unroll
    for (int m = 1; m < 64; m <<= 1) {
        int v = __shfl_up(incl, m, 64);
        if (lane >= m) incl += v;
    }
    if (lane == 63) wsum[wv] = incl;
    __syncthreads();
    if (tid < 16) {
        int v = wsum[tid];
#pragma unroll
        for (int m = 1; m < 16; m <<= 1) {
            int u = __shfl_up(v, m, 64);
            if (tid >= m) v += u;
        }
        wpre[tid] = v;
    }
    __syncthreads();
    int waveoff = (wv == 0) ? 0 : wpre[wv - 1];
    int run = waveoff + incl - s;
    for (int i = 0; i < CH; i++) {
        int idx = base + i;
        if (idx < NNODE) {
            off[idx] = run;
            run += deg[idx];
        }
    }
    if (tid == 0) off[NNODE] = wpre[15];
}

// XCD-sliced payload placement: slice = blockIdx&7 (round-robin XCD heuristic).
__global__ __launch_bounds__(256) void k_place_sliced(
    const int* __restrict__ rA, const int* __restrict__ cA,
    const int* __restrict__ rE, const int* __restrict__ cE,
    const int* __restrict__ rR, const int* __restrict__ cR,
    const int* __restrict__ ridx, const float* __restrict__ rval,
    const float* __restrict__ nrm,
    const int* __restrict__ oA, const int* __restrict__ oE, const int* __restrict__ oR,
    int* __restrict__ cntA, int* __restrict__ cntE, int* __restrict__ cntR,
    int2* __restrict__ ePackSc, int* __restrict__ eColE, int* __restrict__ eColR) {
    int slice = blockIdx.x & (NSLICE - 1);
    int t = (blockIdx.x >> 3) * 256 + threadIdx.x;
    if (t >= NTRI) return;
    int lo = slice * SLICE_ROWS;
    int r = rA[t];
    if ((unsigned)(r - lo) < (unsigned)SLICE_ROWS) {
        int rid = ridx[t];
        float v = rval[t];
        float sc = v / fmaxf(fabsf(v) * nrm[rid], EPSN);
        int p = oA[r] + atomicAdd(&cntA[r], 1);
        ePackSc[p] = make_int2(cA[t] | (rid << 16), __float_as_int(sc));
    }
    r = rE[t];
    if ((unsigned)(r - lo) < (unsigned)SLICE_ROWS)
        eColE[oE[r] + atomicAdd(&cntE[r], 1)] = cE[t];
    r = rR[t];
    if ((unsigned)(r - lo) < (unsigned)SLICE_ROWS)
        eColR[oR[r] + atomicAdd(&cntR[r], 1)] = cR[t];
}

// ---------------- small precomputes ----------------
__global__ void k_relprep(const float* __restrict__ rel_emb,
                          const float* __restrict__ e_attn, const float* __restrict__ r_attn,
                          float* __restrict__ nrm, float2* __restrict__ attL0,
                          float2* __restrict__ attL1) {
    int r = blockIdx.x;
    int lane = threadIdx.x;
    float a = rel_emb[r * DIMK + lane];
    float b = rel_emb[r * DIMK + 64 + lane];
    float nn = waveSum(a * a + b * b);
    float d0 = waveSum(a * e_attn[lane] + b * e_attn[64 + lane]);
    float d1 = waveSum(a * e_attn[DIMK + lane] + b * e_attn[DIMK + 64 + lane]);
    float d2 = waveSum(a * r_attn[lane] + b * r_attn[64 + lane]);
    float d3 = waveSum(a * r_attn[DIMK + lane] + b * r_attn[DIMK + 64 + lane]);
    if (lane == 0) {
        nrm[r] = sqrtf(nn);
        attL0[r] = make_float2(d0, d2);
        attL1[r] = make_float2(d1, d3);
    }
}

// both encoders' proxy prep in one dispatch
__global__ void k_proxyprep2(const float* __restrict__ e_proxy, const float* __restrict__ r_proxy,
                             float* __restrict__ pnT_e, float* __restrict__ pnT_r) {
    int enc = blockIdx.x >= NPROX;
    int k = blockIdx.x & (NPROX - 1);
    const float* proxy = enc ? r_proxy : e_proxy;
    float* pnT = enc ? pnT_r : pnT_e;
    int lane = threadIdx.x;
    float v[6];
    float ss = 0.f;
#pragma unroll
    for (int j = 0; j < 6; j++) {
        v[j] = proxy[k * F3 + j * 64 + lane];
        ss += v[j] * v[j];
    }
    ss = waveSum(ss);
    float inv = 1.0f / fmaxf(sqrtf(ss), EPSN);
#pragma unroll
    for (int j = 0; j < 6; j++) pnT[(j * 64 + lane) * NPROX + k] = v[j] * inv;
}

// both encoders' gate prep in one dispatch
__global__ void k_gateprep2(const float* __restrict__ e_gate, const float* __restrict__ r_gate,
                            ushort_t* __restrict__ the, ushort_t* __restrict__ tle,
                            ushort_t* __restrict__ thr, ushort_t* __restrict__ tlr) {
    int enc = blockIdx.x >= F3;
    int k = enc ? blockIdx.x - F3 : blockIdx.x;
    const float* g = enc ? r_gate : e_gate;
    ushort_t* th = enc ? thr : the;
    ushort_t* tl = enc ? tlr : tle;
    int c = threadIdx.x;
    float v = g[(size_t)k * F3 + c];
    unsigned int b = __float_as_uint(v);
    th[(size_t)c * F3 + k] = (ushort_t)(b >> 16);
    float lo = v - __uint_as_float(b & 0xffff0000u);
    tl[(size_t)c * F3 + k] = (ushort_t)(__float_as_uint(lo) >> 16);
}

// ---------------- fused neighbor mean + tanh ----------------
__global__ __launch_bounds__(256) void k_avg2(
    const int* __restrict__ offE, const int* __restrict__ eColE, const float* __restrict__ ent_emb,
    const int* __restrict__ offR, const int* __restrict__ eColR, const float* __restrict__ rel_emb,
    float* __restrict__ out_e, float* __restrict__ out_r) {
    int gw = (blockIdx.x * blockDim.x + threadIdx.x) >> 6;
    int lane = threadIdx.x & 63;
    if (gw >= 2 * NNODE) return;
    bool isR = gw >= NNODE;
    int wid = isR ? gw - NNODE : gw;
    const int* off = isR ? offR : offE;
    const int* ecol = isR ? eColR : eColE;
    const float4* emb4 = (const float4*)(isR ? rel_emb : ent_emb);
    float* outp = isR ? out_r : out_e;
    int q = lane >> 4, ql = lane & 15;
    int e0 = off[wid], e1 = off[wid + 1];
    float4 aA = {0, 0, 0, 0}, aB = {0, 0, 0, 0};
    for (int base = e0; base < e1; base += 64) {
        int n = min(64, e1 - base);
        int mc = (lane < n) ? ecol[base + lane] : -1;
        for (int j = 0; j < n; j += 4) {
            int e = j + q;
            int c = __shfl(mc, e, 64);
            if (e < n) {
                float4 va = emb4[(size_t)c * 32 + ql];
                float4 vb = emb4[(size_t)c * 32 + 16 + ql];
                aA.x += va.x; aA.y += va.y; aA.z += va.z; aA.w += va.w;
                aB.x += vb.x; aB.y += vb.y; aB.z += vb.z; aB.w += vb.w;
            }
        }
    }
    qreduce4(aA);
    qreduce4(aB);
    if (q == 0) {
        float invd = (e1 > e0) ? 1.0f / (float)(e1 - e0) : 0.0f;
        float4* o = (float4*)outp;
        float4 ra = {tanhf(aA.x * invd), tanhf(aA.y * invd), tanhf(aA.z * invd), tanhf(aA.w * invd)};
        float4 rb = {tanhf(aB.x * invd), tanhf(aB.y * invd), tanhf(aB.z * invd), tanhf(aB.w * invd)};
        o[(size_t)wid * 96 + ql] = ra;
        o[(size_t)wid * 96 + 16 + ql] = rb;
    }
}

// ---------------- fused reflection attention aggregation ----------------
__global__ __launch_bounds__(256) void k_agg2(
    const int* __restrict__ off, const int2* __restrict__ ePackSc,
    const float2* __restrict__ attL, const float* __restrict__ rel_emb,
    float* __restrict__ out_e, float* __restrict__ out_r, int lin) {
    int wid = (blockIdx.x * blockDim.x + threadIdx.x) >> 6;
    int lane = threadIdx.x & 63;
    if (wid >= NNODE) return;
    int q = lane >> 4, ql = lane & 15;
    int e0 = off[wid], e1 = off[wid + 1];
    const float4* rel4 = (const float4*)rel_emb;
    const float4* pe4 = (const float4*)out_e;
    const float4* pr4 = (const float4*)out_r;
    int sA = lin * 32 + ql, sB = lin * 32 + 16 + ql;
    float4 aEa = {0, 0, 0, 0}, aEb = {0, 0, 0, 0}, aRa = {0, 0, 0, 0}, aRb = {0, 0, 0, 0};
    float sE = 0.f, sR = 0.f;
    for (int base = e0; base < e1; base += 64) {
        int n = min(64, e1 - base);
        int pk = 0;
        float sc = 0.f, wE = 0.f, wR = 0.f;
        if (lane < n) {
            int2 ps = ePackSc[base + lane];
            pk = ps.x;
            sc = __int_as_float(ps.y);
            float2 a = attL[pk >> 16];
            wE = __expf(sc * a.x);
            wR = __expf(sc * a.y);
        }
        for (int j = 0; j < n; j += 4) {
            int e = j + q;
            int pke = __shfl(pk, e, 64);
            float sce = __shfl(sc, e, 64);
            float wEe = __shfl(wE, e, 64);
            float wRe = __shfl(wR, e, 64);
            int c = pke & 0xFFFF;
            int r = pke >> 16;
            float4 ra = rel4[(size_t)r * 32 + ql];
            float4 rb = rel4[(size_t)r * 32 + 16 + ql];
            float4 fa = pe4[(size_t)c * 96 + sA];
            float4 fb = pe4[(size_t)c * 96 + sB];
            float4 ga = pr4[(size_t)c * 96 + sA];
            float4 gb = pr4[(size_t)c * 96 + sB];
            float tax = sce * ra.x, tay = sce * ra.y, taz = sce * ra.z, taw = sce * ra.w;
            float tbx = sce * rb.x, tby = sce * rb.y, tbz = sce * rb.z, tbw = sce * rb.w;
            float dE = fa.x * tax + fa.y * tay + fa.z * taz + fa.w * taw +
                       fb.x * tbx + fb.y * tby + fb.z * tbz + fb.w * tbw;
            float dR = ga.x * tax + ga.y * tay + ga.z * taz + ga.w * taw +
                       gb.x * tbx + gb.y * tby + gb.z * tbz + gb.w * tbw;
#pragma unroll
            for (int m = 1; m <= 8; m <<= 1) {
                dE += __shfl_xor(dE, m, 64);
                dR += __shfl_xor(dR, m, 64);
            }
            dE *= 2.f;
            dR *= 2.f;
            aEa.x += wEe * (fa.x - dE * tax);
            aEa.y += wEe * (fa.y - dE * tay);
            aEa.z += wEe * (fa.z - dE * taz);
            aEa.w += wEe * (fa.w - dE * taw);
            aEb.x += wEe * (fb.x - dE * tbx);
            aEb.y += wEe * (fb.y - dE * tby);
            aEb.z += wEe * (fb.z - dE * tbz);
            aEb.w += wEe * (fb.w - dE * tbw);
            aRa.x += wRe * (ga.x - dR * tax);
            aRa.y += wRe * (ga.y - dR * tay);
            aRa.z += wRe * (ga.z - dR * taz);
            aRa.w += wRe * (ga.w - dR * taw);
            aRb.x += wRe * (gb.x - dR * tbx);
            aRb.y += wRe * (gb.y - dR * tby);
            aRb.z += wRe * (gb.z - dR * tbz);
            aRb.w += wRe * (gb.w - dR * tbw);
            sE += wEe;
            sR += wRe;
        }
    }
    qreduce4(aEa);
    qreduce4(aEb);
    qreduce4(aRa);
    qreduce4(aRb);
#pragma unroll
    for (int m = 16; m <= 32; m <<= 1) {
        sE += __shfl_xor(sE, m, 64);
        sR += __shfl_xor(sR, m, 64);
    }
    if (q == 0) {
        float iE = (e1 > e0) ? 1.f / sE : 0.f;
        float4* o = (float4*)out_e;
        float4 wa = {tanhf(aEa.x * iE), tanhf(aEa.y * iE), tanhf(aEa.z * iE), tanhf(aEa.w * iE)};
        float4 wb = {tanhf(aEb.x * iE), tanhf(aEb.y * iE), tanhf(aEb.z * iE), tanhf(aEb.w * iE)};
        o[(size_t)wid * 96 + (lin + 1) * 32 + ql] = wa;
        o[(size_t)wid * 96 + (lin + 1) * 32 + 16 + ql] = wb;
    } else if (q == 1) {
        float iR = (e1 > e0) ? 1.f / sR : 0.f;
        float4* o = (float4*)out_r;
        float4 wa = {tanhf(aRa.x * iR), tanhf(aRa.y * iR), tanhf(aRa.z * iR), tanhf(aRa.w * iR)};
        float4 wb = {tanhf(aRb.x * iR), tanhf(aRb.y * iR), tanhf(aRb.z * iR), tanhf(aRb.w * iR)};
        o[(size_t)wid * 96 + (lin + 1) * 32 + ql] = wa;
        o[(size_t)wid * 96 + (lin + 1) * 32 + 16 + ql] = wb;
    }
}

// ---------------- epilogue (z = encoder) ----------------
__global__ void k_scores(const float* __restrict__ out_e, const float* __restrict__ out_r,
                         const float* __restrict__ pnT_e, const float* __restrict__ pnT_r,
                         float* __restrict__ pa_e, float* __restrict__ pa_r) {
    const float* outb = blockIdx.z ? out_r : out_e;
    const float* pnT = blockIdx.z ? pnT_r : pnT_e;
    float* pa = blockIdx.z ? pa_r : pa_e;
    __shared__ __align__(16) float As[16][68];
    __shared__ __align__(16) float Bs[16][68];
    __shared__ float Ss[64][65];
    __shared__ float rnS[64];
    int tid = threadIdx.x;
    int row0 = blockIdx.x * 64;
    int kk = tid & 15, rr = tid >> 4;
    int cb = tid & 63, kb = tid >> 6;
    int tx = tid & 15, ty = tid >> 4;
    int c0 = tx * 4, r0 = ty * 4;
    float acc[4][4] = {};
    float ssp[4] = {};
    for (int k0 = 0; k0 < F3; k0 += 16) {
#pragma unroll
        for (int u = 0; u < 4; u++) {
            int r = rr + u * 16;
            float v = outb[(size_t)(row0 + r) * F3 + k0 + kk];
            As[kk][r] = v;
            ssp[u] += v * v;
        }
#pragma unroll
        for (int u = 0; u < 4; u++) {
            int k = kb + u * 4;
            Bs[k][cb] = pnT[(size_t)(k0 + k) * NPROX + cb];
        }
        __syncthreads();
#pragma unroll
        for (int k = 0; k < 16; k++) {
            float4 av = *(const float4*)&As[k][r0];
            float4 bv = *(const float4*)&Bs[k][c0];
            float a[4] = {av.x, av.y, av.z, av.w};
            float b[4] = {bv.x, bv.y, bv.z, bv.w};
#pragma unroll
            for (int i = 0; i < 4; i++)
#pragma unroll
                for (int j = 0; j < 4; j++) acc[i][j] += a[i] * b[j];
        }
        __syncthreads();
    }
#pragma unroll
    for (int u = 0; u < 4; u++) {
        float ss = ssp[u];
#pragma unroll
        for (int m = 1; m < 16; m <<= 1) ss += __shfl_xor(ss, m, 64);
        if (kk == 0) rnS[rr + u * 16] = 1.0f / fmaxf(sqrtf(ss), EPSN);
    }
    __syncthreads();
#pragma unroll
    for (int i = 0; i < 4; i++) {
        float rn = rnS[r0 + i];
#pragma unroll
        for (int j = 0; j < 4; j++) Ss[r0 + i][c0 + j] = acc[i][j] * rn;
    }
    __syncthreads();
    if (tid < 64) {
        int r = tid;
        float m = -1e30f;
        for (int c = 0; c < 64; c++) m = fmaxf(m, Ss[r][c]);
        float s = 0.f;
        for (int c = 0; c < 64; c++) s += expf(Ss[r][c] - m);
        float inv = 1.f / s;
        float* po = pa + (size_t)(row0 + r) * NPROX;
        for (int c = 0; c < 64; c++) po[c] = expf(Ss[r][c] - m) * inv;
    }
}

__global__ void k_pf(const float* __restrict__ pa_e, const float* __restrict__ pa_r,
                     const float* __restrict__ e_proxy, const float* __restrict__ r_proxy,
                     const float* __restrict__ out_e, const float* __restrict__ out_r,
                     ushort_t* __restrict__ pfh_e, ushort_t* __restrict__ pfl_e,
                     ushort_t* __restrict__ pfh_r, ushort_t* __restrict__ pfl_r) {
    const float* pa = blockIdx.z ? pa_r : pa_e;
    const float* proxy = blockIdx.z ? r_proxy : e_proxy;
    const float* outb = blockIdx.z ? out_r : out_e;
    ushort_t* pfh = blockIdx.z ? pfh_r : pfh_e;
    ushort_t* pfl = blockIdx.z ? pfl_r : pfl_e;
    __shared__ __align__(16) float As[16][68];
    __shared__ __align__(16) float Bs[16][68];
    int tid = threadIdx.x;
    int row0 = blockIdx.x * 64;
    int col0 = blockIdx.y * 64;
    int kk = tid & 15, rr = tid >> 4;
    int cb = tid & 63, kb = tid >> 6;
    int tx = tid & 15, ty = tid >> 4;
    int c0 = tx * 4, r0 = ty * 4;
    float acc[4][4] = {};
    for (int k0 = 0; k0 < NPROX; k0 += 16) {
#pragma unroll
        for (int u = 0; u < 4; u++) {
            int r = rr + u * 16;
            As[kk][r] = pa[(size_t)(row0 + r) * NPROX + k0 + kk];
        }
#pragma unroll
        for (int u = 0; u < 4; u++) {
            int k = kb + u * 4;
            Bs[k][cb] = proxy[(size_t)(k0 + k) * F3 + col0 + cb];
        }
        __syncthreads();
#pragma unroll
        for (int k = 0; k < 16; k++) {
            float4 av = *(const float4*)&As[k][r0];
            float4 bv = *(const float4*)&Bs[k][c0];
            float a[4] = {av.x, av.y, av.z, av.w};
            float b[4] = {bv.x, bv.y, bv.z, bv.w};
#pragma unroll
            for (int i = 0; i < 4; i++)
#pragma unroll
                for (int j = 0; j < 4; j++) acc[i][j] += a[i] * b[j];
        }
        __syncthreads();
    }
#pragma unroll
    for (int i = 0; i < 4; i++)
#pragma unroll
        for (int j = 0; j < 4; j++) {
            size_t idx = (size_t)(row0 + r0 + i) * F3 + col0 + c0 + j;
            float v = outb[idx] - acc[i][j];
            unsigned int b = __float_as_uint(v);
            pfh[idx] = (ushort_t)(b >> 16);
            float lo = v - __uint_as_float(b & 0xffff0000u);
            pfl[idx] = (ushort_t)(__float_as_uint(lo) >> 16);
        }
}

// LDS-staged gate GEMM with T14 reg-prefetch pipeline.
// R2 post-mortem: direct-global A reads were uncoalesced (16 lines/instr) ->
// regressed. LDS staging IS the coalescer; the R1 cost was serial load latency
// per k-step. Fix: prologue-load A(k0=0) to regs; per step, ds_write staged
// regs, issue B(k0) + A(k0+32) loads, then barrier + ds_read + MFMA. Load
// latency hides under a full step of compute.
__global__ __launch_bounds__(256) void k_gate_mfma(
    const ushort_t* __restrict__ pfh_e, const ushort_t* __restrict__ pfl_e,
    const ushort_t* __restrict__ pfh_r, const ushort_t* __restrict__ pfl_r,
    const ushort_t* __restrict__ gTh_e, const ushort_t* __restrict__ gTl_e,
    const ushort_t* __restrict__ gTh_r, const ushort_t* __restrict__ gTl_r,
    const float* __restrict__ e_bias, const float* __restrict__ r_bias,
    const float* __restrict__ out_e, const float* __restrict__ out_r,
    float* __restrict__ dout) {
    const ushort_t* pfh = blockIdx.z ? pfh_r : pfh_e;
    const ushort_t* pfl = blockIdx.z ? pfl_r : pfl_e;
    const ushort_t* gTh = blockIdx.z ? gTh_r : gTh_e;
    const ushort_t* gTl = blockIdx.z ? gTl_r : gTl_e;
    const float* bias = blockIdx.z ? r_bias : e_bias;
    const float* outb = blockIdx.z ? out_r : out_e;
    int outoff = blockIdx.z ? F3 : 0;
    __shared__ __align__(16) ushort_t AsH[128 * 40];
    __shared__ __align__(16) ushort_t AsL[128 * 40];
    int tid = threadIdx.x;
    int w = tid >> 6, lane = tid & 63;
    int quad = lane >> 4, l16 = lane & 15;
    int wrow = (w >> 1) * 64, wcol = (w & 1) * 64;
    int gr0 = blockIdx.x * 128;
    int cb0 = blockIdx.y * 128;
    f32x4 acc[4][4];
#pragma unroll
    for (int rt = 0; rt < 4; rt++)
#pragma unroll
        for (int ct = 0; ct < 4; ct++) acc[rt][ct] = (f32x4){0.f, 0.f, 0.f, 0.f};

    int srow = tid >> 2, sseg = tid & 3;
    int gr_u0 = gr0 + srow;
    int gr_u1 = gr0 + srow + 64;
    uint4 pvh0, pvl0, pvh1, pvl1;
    // prologue prefetch for k0 = 0
    {
        uint4 z = {0, 0, 0, 0};
        pvh0 = pvl0 = pvh1 = pvl1 = z;
        if (gr_u0 < NNODE) {
            pvh0 = *(const uint4*)&pfh[(size_t)gr_u0 * F3 + sseg * 8];
            pvl0 = *(const uint4*)&pfl[(size_t)gr_u0 * F3 + sseg * 8];
        }
        if (gr_u1 < NNODE) {
            pvh1 = *(const uint4*)&pfh[(size_t)gr_u1 * F3 + sseg * 8];
            pvl1 = *(const uint4*)&pfl[(size_t)gr_u1 * F3 + sseg * 8];
        }
    }
    for (int k0 = 0; k0 < F3; k0 += 32) {
        __syncthreads();  // previous step's consumers done with LDS
        *(uint4*)&AsH[srow * 40 + sseg * 8] = pvh0;
        *(uint4*)&AsL[srow * 40 + sseg * 8] = pvl0;
        *(uint4*)&AsH[(srow + 64) * 40 + sseg * 8] = pvh1;
        *(uint4*)&AsL[(srow + 64) * 40 + sseg * 8] = pvl1;
        // issue B loads for CURRENT step (L2-hot; latency hides under barrier+ds_read)
        bf16x8 bh[4], bl[4];
#pragma unroll
        for (int ct = 0; ct < 4; ct++) {
            int bc = cb0 + wcol + ct * 16 + l16;
            bh[ct] = *(const bf16x8*)&gTh[(size_t)bc * F3 + k0 + quad * 8];
            bl[ct] = *(const bf16x8*)&gTl[(size_t)bc * F3 + k0 + quad * 8];
        }
        // prefetch A panel for NEXT step (HBM/L3 latency hides under MFMA phase)
        int kn = k0 + 32;
        if (kn < F3) {
            if (gr_u0 < NNODE) {
                pvh0 = *(const uint4*)&pfh[(size_t)gr_u0 * F3 + kn + sseg * 8];
                pvl0 = *(const uint4*)&pfl[(size_t)gr_u0 * F3 + kn + sseg * 8];
            }
            if (gr_u1 < NNODE) {
                pvh1 = *(const uint4*)&pfh[(size_t)gr_u1 * F3 + kn + sseg * 8];
                pvl1 = *(const uint4*)&pfl[(size_t)gr_u1 * F3 + kn + sseg * 8];
            }
        }
        __syncthreads();  // staged A visible
        bf16x8 ah[4], al[4];
#pragma unroll
        for (int rt = 0; rt < 4; rt++) {
            int ar = wrow + rt * 16 + l16;
            ah[rt] = *(const bf16x8*)&AsH[ar * 40 + quad * 8];
            al[rt] = *(const bf16x8*)&AsL[ar * 40 + quad * 8];
        }
#pragma unroll
        for (int rt = 0; rt < 4; rt++)
#pragma unroll
            for (int ct = 0; ct < 4; ct++) {
                acc[rt][ct] = __builtin_amdgcn_mfma_f32_16x16x32_bf16(ah[rt], bh[ct], acc[rt][ct], 0, 0, 0);
                acc[rt][ct] = __builtin_amdgcn_mfma_f32_16x16x32_bf16(ah[rt], bl[ct], acc[rt][ct], 0, 0, 0);
                acc[rt][ct] = __builtin_amdgcn_mfma_f32_16x16x32_bf16(al[rt], bh[ct], acc[rt][ct], 0, 0, 0);
            }
    }
#pragma unroll
    for (int rt = 0; rt < 4; rt++) {
        int rbase = gr0 + wrow + rt * 16 + quad * 4;
#pragma unroll
        for (int reg = 0; reg < 4; reg++) {
            int row = rbase + reg;
            if (row >= NNODE) continue;
#pragma unroll
            for (int ct = 0; ct < 4; ct++) {
                int c = cb0 + wcol + ct * 16 + l16;
                float x = acc[rt][ct][reg] + bias[c];
                float g = 1.f / (1.f + __expf(-x));
                size_t idx = (size_t)row * F3 + c;
                float pf = bf2f(pfh[idx]) + bf2f(pfl[idx]);
                float o = outb[idx];
                dout[(size_t)row * 768 + outoff + c] = g * o + (1.f - g) * pf;
            }
        }
    }
}

// ---------------- launch ----------------
extern "C" void kernel_launch(void* const* d_in, const int* in_sizes, int n_in,
                              void* d_out, int out_size, void* d_ws, size_t ws_size,
                              hipStream_t stream) {
    const int* ent_adj = (const int*)d_in[0];
    const int* rel_adj = (const int*)d_in[1];
    const int* adj_list = (const int*)d_in[4];
    const int* r_index = (const int*)d_in[5];
    const float* r_val = (const float*)d_in[6];
    const float* ent_emb = (const float*)d_in[9];
    const float* rel_emb = (const float*)d_in[10];
    const float* e_attn = (const float*)d_in[11];
    const float* e_gate = (const float*)d_in[12];
    const float* e_proxy = (const float*)d_in[13];
    const float* e_bias = (const float*)d_in[14];
    const float* r_attn = (const float*)d_in[15];
    const float* r_gate = (const float*)d_in[16];
    const float* r_proxy = (const float*)d_in[17];
    const float* r_bias = (const float*)d_in[18];
    float* out = (float*)d_out;

    char* ws = (char*)d_ws;
    size_t off = 0;
    auto alloc = [&](size_t bytes) -> void* {
        off = (off + 255) & ~(size_t)255;
        void* p = ws + off;
        off += bytes;
        return p;
    };

    int* degcur = (int*)alloc(6 * NNODE * sizeof(int));
    int* degA = degcur, *curA = degcur + NNODE;
    int* degE = degcur + 2 * NNODE, *curE = degcur + 3 * NNODE;
    int* degR = degcur + 4 * NNODE, *curR = degcur + 5 * NNODE;
    int* offA = (int*)alloc((NNODE + 1) * sizeof(int));
    int* offE = (int*)alloc((NNODE + 1) * sizeof(int));
    int* offR = (int*)alloc((NNODE + 1) * sizeof(int));
    int2* ePackSc = (int2*)alloc(NTRI * sizeof(int2));
    int* eColE = (int*)alloc(NTRI * sizeof(int));
    int* eColR = (int*)alloc(NTRI * sizeof(int));
    float* nrm = (float*)alloc(NREL * sizeof(float));
    float2* attL0 = (float2*)alloc(NREL * sizeof(float2));
    float2* attL1 = (float2*)alloc(NREL * sizeof(float2));
    float* pnT_e = (float*)alloc((size_t)F3 * NPROX * sizeof(float));
    float* pnT_r = (float*)alloc((size_t)F3 * NPROX * sizeof(float));
    ushort_t* gTh_e = (ushort_t*)alloc((size_t)F3 * F3 * sizeof(ushort_t));
    ushort_t* gTl_e = (ushort_t*)alloc((size_t)F3 * F3 * sizeof(ushort_t));
    ushort_t* gTh_r = (ushort_t*)alloc((size_t)F3 * F3 * sizeof(ushort_t));
    ushort_t* gTl_r = (ushort_t*)alloc((size_t)F3 * F3 * sizeof(ushort_t));
    float* pa_e = (float*)alloc((size_t)NNODE * NPROX * sizeof(float));
    float* pa_r = (float*)alloc((size_t)NNODE * NPROX * sizeof(float));
    ushort_t* pfh_e = (ushort_t*)alloc((size_t)NNODE * F3 * sizeof(ushort_t));
    ushort_t* pfl_e = (ushort_t*)alloc((size_t)NNODE * F3 * sizeof(ushort_t));
    ushort_t* pfh_r = (ushort_t*)alloc((size_t)NNODE * F3 * sizeof(ushort_t));
    ushort_t* pfl_r = (ushort_t*)alloc((size_t)NNODE * F3 * sizeof(ushort_t));
    float* out_e = (float*)alloc((size_t)NNODE * F3 * sizeof(float));
    float* out_r = (float*)alloc((size_t)NNODE * F3 * sizeof(float));
    (void)ws_size; (void)in_sizes; (void)n_in; (void)out_size;

    hipMemsetAsync(degcur, 0, 6 * NNODE * sizeof(int), stream);

    int gT = (NTRI + 255) / 256;
    k_count3<<<gT, 256, 0, stream>>>(adj_list, ent_adj, rel_adj, degA, degE, degR);
    k_scan_fast<<<3, 1024, 0, stream>>>(degA, offA, degE, offE, degR, offR);
    k_relprep<<<NREL, 64, 0, stream>>>(rel_emb, e_attn, r_attn, nrm, attL0, attL1);
    k_place_sliced<<<gT * NSLICE, 256, 0, stream>>>(
        adj_list, adj_list + NTRI, ent_adj, ent_adj + NTRI, rel_adj, rel_adj + NTRI,
        r_index + NTRI, r_val, nrm, offA, offE, offR, curA, curE, curR,
        ePackSc, eColE, eColR);
    k_proxyprep2<<<2 * NPROX, 64, 0, stream>>>(e_proxy, r_proxy, pnT_e, pnT_r);
    k_gateprep2<<<2 * F3, F3, 0, stream>>>(e_gate, r_gate, gTh_e, gTl_e, gTh_r, gTl_r);

    k_avg2<<<(2 * NNODE) / 4, 256, 0, stream>>>(offE, eColE, ent_emb, offR, eColR, rel_emb,
                                                out_e, out_r);

    int gW = NNODE / 4;
    k_agg2<<<gW, 256, 0, stream>>>(offA, ePackSc, attL0, rel_emb, out_e, out_r, 0);
    k_agg2<<<gW, 256, 0, stream>>>(offA, ePackSc, attL1, rel_emb, out_e, out_r, 1);

    dim3 gS(NNODE / 64, 1, 2);
    dim3 gP(NNODE / 64, F3 / 64, 2);
    dim3 gG((NNODE + 127) / 128, F3 / 128, 2);
    k_scores<<<gS, 256, 0, stream>>>(out_e, out_r, pnT_e, pnT_r, pa_e, pa_r);
    k_pf<<<gP, 256, 0, stream>>>(pa_e, pa_r, e_proxy, r_proxy, out_e, out_r,
                                 pfh_e, pfl_e, pfh_r, pfl_r);
    k_gate_mfma<<<gG, 256, 0, stream>>>(pfh_e, pfl_e, pfh_r, pfl_r, gTh_e, gTl_e, gTh_r, gTl_r,
                                        e_bias, r_bias, out_e, out_r, out);
}

// Round 4
// 949.068 us; speedup vs baseline: 1.0901x; 1.0471x over previous
//
#include <hip/hip_runtime.h>
#include <cmath>

#define NNODE 40000
#define NREL  2000
#define NTRI  600000
#define DIMK  128
#define F3    384
#define NPROX 64
#define EPSN  1e-12f
#define NSLICE 8
#define SLICE_ROWS (NNODE / NSLICE)

typedef unsigned short ushort_t;
typedef __attribute__((ext_vector_type(8))) short bf16x8;
typedef __attribute__((ext_vector_type(4))) float f32x4;

static __device__ __forceinline__ float waveSum(float v) {
#pragma unroll
    for (int m = 32; m >= 1; m >>= 1) v += __shfl_xor(v, m, 64);
    return v;
}

static __device__ __forceinline__ void qreduce4(float4& v) {
#pragma unroll
    for (int m = 16; m <= 32; m <<= 1) {
        v.x += __shfl_xor(v.x, m, 64);
        v.y += __shfl_xor(v.y, m, 64);
        v.z += __shfl_xor(v.z, m, 64);
        v.w += __shfl_xor(v.w, m, 64);
    }
}

// pack two floats into hi-bf16 pair and lo-bf16 pair (truncation split, matches k_gateprep2)
static __device__ __forceinline__ uint2 splitpair(float x, float y) {
    unsigned int bx = __float_as_uint(x), by = __float_as_uint(y);
    unsigned int h = (bx >> 16) | (by & 0xffff0000u);
    float lx = x - __uint_as_float(bx & 0xffff0000u);
    float ly = y - __uint_as_float(by & 0xffff0000u);
    unsigned int l = (__float_as_uint(lx) >> 16) | (__float_as_uint(ly) & 0xffff0000u);
    return make_uint2(h, l);
}

static __device__ __forceinline__ void pack8(const float4& a, const float4& b,
                                             uint4& h, uint4& l) {
    uint2 p0 = splitpair(a.x, a.y);
    uint2 p1 = splitpair(a.z, a.w);
    uint2 p2 = splitpair(b.x, b.y);
    uint2 p3 = splitpair(b.z, b.w);
    h = make_uint4(p0.x, p1.x, p2.x, p3.x);
    l = make_uint4(p0.y, p1.y, p2.y, p3.y);
}

// ---------------- CSR build ----------------
__global__ void k_count3(const int* __restrict__ rA, const int* __restrict__ rE,
                         const int* __restrict__ rR, int* __restrict__ dA,
                         int* __restrict__ dE, int* __restrict__ dR) {
    int t = blockIdx.x * 256 + threadIdx.x;
    if (t < NTRI) {
        atomicAdd(&dA[rA[t]], 1);
        atomicAdd(&dE[rE[t]], 1);
        atomicAdd(&dR[rR[t]], 1);
    }
}

__global__ void k_scan_fast(const int* __restrict__ dA, int* __restrict__ oA,
                            const int* __restrict__ dE, int* __restrict__ oE,
                            const int* __restrict__ dR, int* __restrict__ oR) {
    const int* deg = blockIdx.x == 0 ? dA : (blockIdx.x == 1 ? dE : dR);
    int* off = blockIdx.x == 0 ? oA : (blockIdx.x == 1 ? oE : oR);
    __shared__ int wsum[16];
    __shared__ int wpre[16];
    int tid = threadIdx.x;
    int lane = tid & 63, wv = tid >> 6;
    const int CH = 40;
    int base = tid * CH;
    int s = 0;
    for (int i = 0; i < CH; i++) {
        int idx = base + i;
        s += (idx < NNODE) ? deg[idx] : 0;
    }
    int incl = s;
#pragma unroll
    for (int m = 1; m < 64; m <<= 1) {
        int v = __shfl_up(incl, m, 64);
        if (lane >= m) incl += v;
    }
    if (lane == 63) wsum[wv] = incl;
    __syncthreads();
    if (tid < 16) {
        int v = wsum[tid];
#pragma unroll
        for (int m = 1; m < 16; m <<= 1) {
            int u = __shfl_up(v, m, 64);
            if (tid >= m) v += u;
        }
        wpre[tid] = v;
    }
    __syncthreads();
    int waveoff = (wv == 0) ? 0 : wpre[wv - 1];
    int run = waveoff + incl - s;
    for (int i = 0; i < CH; i++) {
        int idx = base + i;
        if (idx < NNODE) {
            off[idx] = run;
            run += deg[idx];
        }
    }
    if (tid == 0) off[NNODE] = wpre[15];
}

// XCD-sliced payload placement: slice = blockIdx&7 (round-robin XCD heuristic).
__global__ __launch_bounds__(256) void k_place_sliced(
    const int* __restrict__ rA, const int* __restrict__ cA,
    const int* __restrict__ rE, const int* __restrict__ cE,
    const int* __restrict__ rR, const int* __restrict__ cR,
    const int* __restrict__ ridx, const float* __restrict__ rval,
    const float* __restrict__ nrm,
    const int* __restrict__ oA, const int* __restrict__ oE, const int* __restrict__ oR,
    int* __restrict__ cntA, int* __restrict__ cntE, int* __restrict__ cntR,
    int2* __restrict__ ePackSc, int* __restrict__ eColE, int* __restrict__ eColR) {
    int slice = blockIdx.x & (NSLICE - 1);
    int t = (blockIdx.x >> 3) * 256 + threadIdx.x;
    if (t >= NTRI) return;
    int lo = slice * SLICE_ROWS;
    int r = rA[t];
    if ((unsigned)(r - lo) < (unsigned)SLICE_ROWS) {
        int rid = ridx[t];
        float v = rval[t];
        float sc = v / fmaxf(fabsf(v) * nrm[rid], EPSN);
        int p = oA[r] + atomicAdd(&cntA[r], 1);
        ePackSc[p] = make_int2(cA[t] | (rid << 16), __float_as_int(sc));
    }
    r = rE[t];
    if ((unsigned)(r - lo) < (unsigned)SLICE_ROWS)
        eColE[oE[r] + atomicAdd(&cntE[r], 1)] = cE[t];
    r = rR[t];
    if ((unsigned)(r - lo) < (unsigned)SLICE_ROWS)
        eColR[oR[r] + atomicAdd(&cntR[r], 1)] = cR[t];
}

// ---------------- small precomputes ----------------
__global__ void k_relprep(const float* __restrict__ rel_emb,
                          const float* __restrict__ e_attn, const float* __restrict__ r_attn,
                          float* __restrict__ nrm, float2* __restrict__ attL0,
                          float2* __restrict__ attL1) {
    int r = blockIdx.x;
    int lane = threadIdx.x;
    float a = rel_emb[r * DIMK + lane];
    float b = rel_emb[r * DIMK + 64 + lane];
    float nn = waveSum(a * a + b * b);
    float d0 = waveSum(a * e_attn[lane] + b * e_attn[64 + lane]);
    float d1 = waveSum(a * e_attn[DIMK + lane] + b * e_attn[DIMK + 64 + lane]);
    float d2 = waveSum(a * r_attn[lane] + b * r_attn[64 + lane]);
    float d3 = waveSum(a * r_attn[DIMK + lane] + b * r_attn[DIMK + 64 + lane]);
    if (lane == 0) {
        nrm[r] = sqrtf(nn);
        attL0[r] = make_float2(d0, d2);
        attL1[r] = make_float2(d1, d3);
    }
}

// both encoders' proxy prep in one dispatch (normalized proxies, [k][64] layout for k_scores)
__global__ void k_proxyprep2(const float* __restrict__ e_proxy, const float* __restrict__ r_proxy,
                             float* __restrict__ pnT_e, float* __restrict__ pnT_r) {
    int enc = blockIdx.x >= NPROX;
    int k = blockIdx.x & (NPROX - 1);
    const float* proxy = enc ? r_proxy : e_proxy;
    float* pnT = enc ? pnT_r : pnT_e;
    int lane = threadIdx.x;
    float v[6];
    float ss = 0.f;
#pragma unroll
    for (int j = 0; j < 6; j++) {
        v[j] = proxy[k * F3 + j * 64 + lane];
        ss += v[j] * v[j];
    }
    ss = waveSum(ss);
    float inv = 1.0f / fmaxf(sqrtf(ss), EPSN);
#pragma unroll
    for (int j = 0; j < 6; j++) pnT[(j * 64 + lane) * NPROX + k] = v[j] * inv;
}

// both encoders' gate prep in one dispatch: gT[c][k] bf16 hi/lo split
__global__ void k_gateprep2(const float* __restrict__ e_gate, const float* __restrict__ r_gate,
                            ushort_t* __restrict__ the, ushort_t* __restrict__ tle,
                            ushort_t* __restrict__ thr, ushort_t* __restrict__ tlr) {
    int enc = blockIdx.x >= F3;
    int k = enc ? blockIdx.x - F3 : blockIdx.x;
    const float* g = enc ? r_gate : e_gate;
    ushort_t* th = enc ? thr : the;
    ushort_t* tl = enc ? tlr : tle;
    int c = threadIdx.x;
    float v = g[(size_t)k * F3 + c];
    unsigned int b = __float_as_uint(v);
    th[(size_t)c * F3 + k] = (ushort_t)(b >> 16);
    float lo = v - __uint_as_float(b & 0xffff0000u);
    tl[(size_t)c * F3 + k] = (ushort_t)(__float_as_uint(lo) >> 16);
}

// PG = proxy @ gate (negated, for fused gate input) and proxyT, both bf16 hi/lo split,
// [c][p] layout (B-operand fragment layout for the K=64 pa-GEMMs).
__global__ void k_pgprep(const float* __restrict__ e_proxy, const float* __restrict__ r_proxy,
                         const float* __restrict__ e_gate, const float* __restrict__ r_gate,
                         ushort_t* __restrict__ pgTh_e, ushort_t* __restrict__ pgTl_e,
                         ushort_t* __restrict__ prTh_e, ushort_t* __restrict__ prTl_e,
                         ushort_t* __restrict__ pgTh_r, ushort_t* __restrict__ pgTl_r,
                         ushort_t* __restrict__ prTh_r, ushort_t* __restrict__ prTl_r) {
    int enc = blockIdx.y;
    const float* proxy = enc ? r_proxy : e_proxy;
    const float* gate = enc ? r_gate : e_gate;
    ushort_t* pgTh = enc ? pgTh_r : pgTh_e;
    ushort_t* pgTl = enc ? pgTl_r : pgTl_e;
    ushort_t* prTh = enc ? prTh_r : prTh_e;
    ushort_t* prTl = enc ? prTl_r : prTl_e;
    int c = blockIdx.x;
    int p = threadIdx.x;  // 64 threads
    float s = 0.f;
    for (int k = 0; k < F3; k++) s = fmaf(proxy[p * F3 + k], gate[(size_t)k * F3 + c], s);
    float v = -s;  // NEGATED: gate accumulator adds pa@(-PG)
    unsigned int b = __float_as_uint(v);
    pgTh[c * NPROX + p] = (ushort_t)(b >> 16);
    float lo = v - __uint_as_float(b & 0xffff0000u);
    pgTl[c * NPROX + p] = (ushort_t)(__float_as_uint(lo) >> 16);
    float pv = proxy[p * F3 + c];
    unsigned int pb = __float_as_uint(pv);
    prTh[c * NPROX + p] = (ushort_t)(pb >> 16);
    float plo = pv - __uint_as_float(pb & 0xffff0000u);
    prTl[c * NPROX + p] = (ushort_t)(__float_as_uint(plo) >> 16);
}

// ---------------- fused neighbor mean + tanh ----------------
__global__ __launch_bounds__(256) void k_avg2(
    const int* __restrict__ offE, const int* __restrict__ eColE, const float* __restrict__ ent_emb,
    const int* __restrict__ offR, const int* __restrict__ eColR, const float* __restrict__ rel_emb,
    float* __restrict__ out_e, float* __restrict__ out_r) {
    int gw = (blockIdx.x * blockDim.x + threadIdx.x) >> 6;
    int lane = threadIdx.x & 63;
    if (gw >= 2 * NNODE) return;
    bool isR = gw >= NNODE;
    int wid = isR ? gw - NNODE : gw;
    const int* off = isR ? offR : offE;
    const int* ecol = isR ? eColR : eColE;
    const float4* emb4 = (const float4*)(isR ? rel_emb : ent_emb);
    float* outp = isR ? out_r : out_e;
    int q = lane >> 4, ql = lane & 15;
    int e0 = off[wid], e1 = off[wid + 1];
    float4 aA = {0, 0, 0, 0}, aB = {0, 0, 0, 0};
    for (int base = e0; base < e1; base += 64) {
        int n = min(64, e1 - base);
        int mc = (lane < n) ? ecol[base + lane] : -1;
        for (int j = 0; j < n; j += 4) {
            int e = j + q;
            int c = __shfl(mc, e, 64);
            if (e < n) {
                float4 va = emb4[(size_t)c * 32 + ql];
                float4 vb = emb4[(size_t)c * 32 + 16 + ql];
                aA.x += va.x; aA.y += va.y; aA.z += va.z; aA.w += va.w;
                aB.x += vb.x; aB.y += vb.y; aB.z += vb.z; aB.w += vb.w;
            }
        }
    }
    qreduce4(aA);
    qreduce4(aB);
    if (q == 0) {
        float invd = (e1 > e0) ? 1.0f / (float)(e1 - e0) : 0.0f;
        float4* o = (float4*)outp;
        float4 ra = {tanhf(aA.x * invd), tanhf(aA.y * invd), tanhf(aA.z * invd), tanhf(aA.w * invd)};
        float4 rb = {tanhf(aB.x * invd), tanhf(aB.y * invd), tanhf(aB.z * invd), tanhf(aB.w * invd)};
        o[(size_t)wid * 96 + ql] = ra;
        o[(size_t)wid * 96 + 16 + ql] = rb;
    }
}

// ---------------- fused reflection attention aggregation ----------------
__global__ __launch_bounds__(256) void k_agg2(
    const int* __restrict__ off, const int2* __restrict__ ePackSc,
    const float2* __restrict__ attL, const float* __restrict__ rel_emb,
    float* __restrict__ out_e, float* __restrict__ out_r, int lin) {
    int wid = (blockIdx.x * blockDim.x + threadIdx.x) >> 6;
    int lane = threadIdx.x & 63;
    if (wid >= NNODE) return;
    int q = lane >> 4, ql = lane & 15;
    int e0 = off[wid], e1 = off[wid + 1];
    const float4* rel4 = (const float4*)rel_emb;
    const float4* pe4 = (const float4*)out_e;
    const float4* pr4 = (const float4*)out_r;
    int sA = lin * 32 + ql, sB = lin * 32 + 16 + ql;
    float4 aEa = {0, 0, 0, 0}, aEb = {0, 0, 0, 0}, aRa = {0, 0, 0, 0}, aRb = {0, 0, 0, 0};
    float sE = 0.f, sR = 0.f;
    for (int base = e0; base < e1; base += 64) {
        int n = min(64, e1 - base);
        int pk = 0;
        float sc = 0.f, wE = 0.f, wR = 0.f;
        if (lane < n) {
            int2 ps = ePackSc[base + lane];
            pk = ps.x;
            sc = __int_as_float(ps.y);
            float2 a = attL[pk >> 16];
            wE = __expf(sc * a.x);
            wR = __expf(sc * a.y);
        }
        for (int j = 0; j < n; j += 4) {
            int e = j + q;
            int pke = __shfl(pk, e, 64);
            float sce = __shfl(sc, e, 64);
            float wEe = __shfl(wE, e, 64);
            float wRe = __shfl(wR, e, 64);
            int c = pke & 0xFFFF;
            int r = pke >> 16;
            float4 ra = rel4[(size_t)r * 32 + ql];
            float4 rb = rel4[(size_t)r * 32 + 16 + ql];
            float4 fa = pe4[(size_t)c * 96 + sA];
            float4 fb = pe4[(size_t)c * 96 + sB];
            float4 ga = pr4[(size_t)c * 96 + sA];
            float4 gb = pr4[(size_t)c * 96 + sB];
            float tax = sce * ra.x, tay = sce * ra.y, taz = sce * ra.z, taw = sce * ra.w;
            float tbx = sce * rb.x, tby = sce * rb.y, tbz = sce * rb.z, tbw = sce * rb.w;
            float dE = fa.x * tax + fa.y * tay + fa.z * taz + fa.w * taw +
                       fb.x * tbx + fb.y * tby + fb.z * tbz + fb.w * tbw;
            float dR = ga.x * tax + ga.y * tay + ga.z * taz + ga.w * taw +
                       gb.x * tbx + gb.y * tby + gb.z * tbz + gb.w * tbw;
#pragma unroll
            for (int m = 1; m <= 8; m <<= 1) {
                dE += __shfl_xor(dE, m, 64);
                dR += __shfl_xor(dR, m, 64);
            }
            dE *= 2.f;
            dR *= 2.f;
            aEa.x += wEe * (fa.x - dE * tax);
            aEa.y += wEe * (fa.y - dE * tay);
            aEa.z += wEe * (fa.z - dE * taz);
            aEa.w += wEe * (fa.w - dE * taw);
            aEb.x += wEe * (fb.x - dE * tbx);
            aEb.y += wEe * (fb.y - dE * tby);
            aEb.z += wEe * (fb.z - dE * tbz);
            aEb.w += wEe * (fb.w - dE * tbw);
            aRa.x += wRe * (ga.x - dR * tax);
            aRa.y += wRe * (ga.y - dR * tay);
            aRa.z += wRe * (ga.z - dR * taz);
            aRa.w += wRe * (ga.w - dR * taw);
            aRb.x += wRe * (gb.x - dR * tbx);
            aRb.y += wRe * (gb.y - dR * tby);
            aRb.z += wRe * (gb.z - dR * tbz);
            aRb.w += wRe * (gb.w - dR * tbw);
            sE += wEe;
            sR += wRe;
        }
    }
    qreduce4(aEa);
    qreduce4(aEb);
    qreduce4(aRa);
    qreduce4(aRb);
#pragma unroll
    for (int m = 16; m <= 32; m <<= 1) {
        sE += __shfl_xor(sE, m, 64);
        sR += __shfl_xor(sR, m, 64);
    }
    if (q == 0) {
        float iE = (e1 > e0) ? 1.f / sE : 0.f;
        float4* o = (float4*)out_e;
        float4 wa = {tanhf(aEa.x * iE), tanhf(aEa.y * iE), tanhf(aEa.z * iE), tanhf(aEa.w * iE)};
        float4 wb = {tanhf(aEb.x * iE), tanhf(aEb.y * iE), tanhf(aEb.z * iE), tanhf(aEb.w * iE)};
        o[(size_t)wid * 96 + (lin + 1) * 32 + ql] = wa;
        o[(size_t)wid * 96 + (lin + 1) * 32 + 16 + ql] = wb;
    } else if (q == 1) {
        float iR = (e1 > e0) ? 1.f / sR : 0.f;
        float4* o = (float4*)out_r;
        float4 wa = {tanhf(aRa.x * iR), tanhf(aRa.y * iR), tanhf(aRa.z * iR), tanhf(aRa.w * iR)};
        float4 wb = {tanhf(aRb.x * iR), tanhf(aRb.y * iR), tanhf(aRb.z * iR), tanhf(aRb.w * iR)};
        o[(size_t)wid * 96 + (lin + 1) * 32 + ql] = wa;
        o[(size_t)wid * 96 + (lin + 1) * 32 + 16 + ql] = wb;
    }
}

// ---------------- epilogue (z = encoder) ----------------
// proxy-attention scores + softmax; emits pa in bf16 hi/lo split (MFMA A-operand form)
__global__ void k_scores(const float* __restrict__ out_e, const float* __restrict__ out_r,
                         const float* __restrict__ pnT_e, const float* __restrict__ pnT_r,
                         ushort_t* __restrict__ paH_e, ushort_t* __restrict__ paL_e,
                         ushort_t* __restrict__ paH_r, ushort_t* __restrict__ paL_r) {
    const float* outb = blockIdx.z ? out_r : out_e;
    const float* pnT = blockIdx.z ? pnT_r : pnT_e;
    ushort_t* paH = blockIdx.z ? paH_r : paH_e;
    ushort_t* paL = blockIdx.z ? paL_r : paL_e;
    __shared__ __align__(16) float As[16][68];
    __shared__ __align__(16) float Bs[16][68];
    __shared__ float Ss[64][65];
    __shared__ float rnS[64];
    int tid = threadIdx.x;
    int row0 = blockIdx.x * 64;
    int kk = tid & 15, rr = tid >> 4;
    int cb = tid & 63, kb = tid >> 6;
    int tx = tid & 15, ty = tid >> 4;
    int c0 = tx * 4, r0 = ty * 4;
    float acc[4][4] = {};
    float ssp[4] = {};
    for (int k0 = 0; k0 < F3; k0 += 16) {
#pragma unroll
        for (int u = 0; u < 4; u++) {
            int r = rr + u * 16;
            float v = outb[(size_t)(row0 + r) * F3 + k0 + kk];
            As[kk][r] = v;
            ssp[u] += v * v;
        }
#pragma unroll
        for (int u = 0; u < 4; u++) {
            int k = kb + u * 4;
            Bs[k][cb] = pnT[(size_t)(k0 + k) * NPROX + cb];
        }
        __syncthreads();
#pragma unroll
        for (int k = 0; k < 16; k++) {
            float4 av = *(const float4*)&As[k][r0];
            float4 bv = *(const float4*)&Bs[k][c0];
            float a[4] = {av.x, av.y, av.z, av.w};
            float b[4] = {bv.x, bv.y, bv.z, bv.w};
#pragma unroll
            for (int i = 0; i < 4; i++)
#pragma unroll
                for (int j = 0; j < 4; j++) acc[i][j] += a[i] * b[j];
        }
        __syncthreads();
    }
#pragma unroll
    for (int u = 0; u < 4; u++) {
        float ss = ssp[u];
#pragma unroll
        for (int m = 1; m < 16; m <<= 1) ss += __shfl_xor(ss, m, 64);
        if (kk == 0) rnS[rr + u * 16] = 1.0f / fmaxf(sqrtf(ss), EPSN);
    }
    __syncthreads();
#pragma unroll
    for (int i = 0; i < 4; i++) {
        float rn = rnS[r0 + i];
#pragma unroll
        for (int j = 0; j < 4; j++) Ss[r0 + i][c0 + j] = acc[i][j] * rn;
    }
    __syncthreads();
    if (tid < 64) {
        int r = tid;
        float m = -1e30f;
        for (int c = 0; c < 64; c++) m = fmaxf(m, Ss[r][c]);
        float s = 0.f;
        for (int c = 0; c < 64; c++) s += expf(Ss[r][c] - m);
        float inv = 1.f / s;
        size_t base = (size_t)(row0 + r) * NPROX;
        for (int c = 0; c < 64; c++) {
            float v = expf(Ss[r][c] - m) * inv;
            unsigned int b = __float_as_uint(v);
            paH[base + c] = (ushort_t)(b >> 16);
            float lo = v - __uint_as_float(b & 0xffff0000u);
            paL[base + c] = (ushort_t)(__float_as_uint(lo) >> 16);
        }
    }
}

// Fused gate+pf kernel. k_pf is ELIMINATED:
//   gate input x = pf@gate = out@gate + pa@(-PG)    (PG = proxy@gate precomputed)
//   Z = pa@proxy; dout = g*out + (1-g)*(out - Z) = out - (1-g)*Z
// A-panel = out (f32) split to bf16 hi/lo on the fly during LDS staging (same bytes
// staged as old pfh/pfl). 64-col blocks (grid y=6) double resident blocks for the
// latency-bound regime. R3 T14 reg-prefetch pipeline retained.
__global__ __launch_bounds__(256) void k_gate_fused(
    const ushort_t* __restrict__ paH_e, const ushort_t* __restrict__ paL_e,
    const ushort_t* __restrict__ paH_r, const ushort_t* __restrict__ paL_r,
    const ushort_t* __restrict__ gTh_e, const ushort_t* __restrict__ gTl_e,
    const ushort_t* __restrict__ gTh_r, const ushort_t* __restrict__ gTl_r,
    const ushort_t* __restrict__ pgTh_e, const ushort_t* __restrict__ pgTl_e,
    const ushort_t* __restrict__ prTh_e, const ushort_t* __restrict__ prTl_e,
    const ushort_t* __restrict__ pgTh_r, const ushort_t* __restrict__ pgTl_r,
    const ushort_t* __restrict__ prTh_r, const ushort_t* __restrict__ prTl_r,
    const float* __restrict__ e_bias, const float* __restrict__ r_bias,
    const float* __restrict__ out_e, const float* __restrict__ out_r,
    float* __restrict__ dout) {
    const ushort_t* paH = blockIdx.z ? paH_r : paH_e;
    const ushort_t* paL = blockIdx.z ? paL_r : paL_e;
    const ushort_t* gTh = blockIdx.z ? gTh_r : gTh_e;
    const ushort_t* gTl = blockIdx.z ? gTl_r : gTl_e;
    const ushort_t* pgTh = blockIdx.z ? pgTh_r : pgTh_e;
    const ushort_t* pgTl = blockIdx.z ? pgTl_r : pgTl_e;
    const ushort_t* prTh = blockIdx.z ? prTh_r : prTh_e;
    const ushort_t* prTl = blockIdx.z ? prTl_r : prTl_e;
    const float* bias = blockIdx.z ? r_bias : e_bias;
    const float* outb = blockIdx.z ? out_r : out_e;
    int outoff = blockIdx.z ? F3 : 0;
    __shared__ __align__(16) ushort_t AsH[128 * 40];
    __shared__ __align__(16) ushort_t AsL[128 * 40];
    int tid = threadIdx.x;
    int w = tid >> 6, lane = tid & 63;
    int quad = lane >> 4, l16 = lane & 15;
    int wrow = (w >> 1) * 64, wcol = (w & 1) * 32;
    int gr0 = blockIdx.x * 128;
    int cb0 = blockIdx.y * 64;
    f32x4 accg[4][2], accp[4][2];
#pragma unroll
    for (int rt = 0; rt < 4; rt++)
#pragma unroll
        for (int ct = 0; ct < 2; ct++) {
            accg[rt][ct] = (f32x4){0.f, 0.f, 0.f, 0.f};
            accp[rt][ct] = (f32x4){0.f, 0.f, 0.f, 0.f};
        }

    int srow = tid >> 2, sseg = tid & 3;
    int gr_u0 = gr0 + srow;
    int gr_u1 = gr0 + srow + 64;
    float4 p0a, p0b, p1a, p1b;
    {
        float4 z = {0, 0, 0, 0};
        p0a = p0b = p1a = p1b = z;
        if (gr_u0 < NNODE) {
            p0a = *(const float4*)&outb[(size_t)gr_u0 * F3 + sseg * 8];
            p0b = *(const float4*)&outb[(size_t)gr_u0 * F3 + sseg * 8 + 4];
        }
        if (gr_u1 < NNODE) {
            p1a = *(const float4*)&outb[(size_t)gr_u1 * F3 + sseg * 8];
            p1b = *(const float4*)&outb[(size_t)gr_u1 * F3 + sseg * 8 + 4];
        }
    }
    for (int k0 = 0; k0 < F3; k0 += 32) {
        __syncthreads();  // previous step's consumers done with LDS
        uint4 h0, l0, h1, l1;
        pack8(p0a, p0b, h0, l0);
        pack8(p1a, p1b, h1, l1);
        *(uint4*)&AsH[srow * 40 + sseg * 8] = h0;
        *(uint4*)&AsL[srow * 40 + sseg * 8] = l0;
        *(uint4*)&AsH[(srow + 64) * 40 + sseg * 8] = h1;
        *(uint4*)&AsL[(srow + 64) * 40 + sseg * 8] = l1;
        // B loads for CURRENT step (L2-hot)
        bf16x8 bh[2], bl[2];
#pragma unroll
        for (int ct = 0; ct < 2; ct++) {
            int bc = cb0 + wcol + ct * 16 + l16;
            bh[ct] = *(const bf16x8*)&gTh[(size_t)bc * F3 + k0 + quad * 8];
            bl[ct] = *(const bf16x8*)&gTl[(size_t)bc * F3 + k0 + quad * 8];
        }
        // prefetch A panel (f32) for NEXT step
        int kn = k0 + 32;
        if (kn < F3) {
            if (gr_u0 < NNODE) {
                p0a = *(const float4*)&outb[(size_t)gr_u0 * F3 + kn + sseg * 8];
                p0b = *(const float4*)&outb[(size_t)gr_u0 * F3 + kn + sseg * 8 + 4];
            }
            if (gr_u1 < NNODE) {
                p1a = *(const float4*)&outb[(size_t)gr_u1 * F3 + kn + sseg * 8];
                p1b = *(const float4*)&outb[(size_t)gr_u1 * F3 + kn + sseg * 8 + 4];
            }
        }
        __syncthreads();  // staged A visible
        bf16x8 ah[4], al[4];
#pragma unroll
        for (int rt = 0; rt < 4; rt++) {
            int ar = wrow + rt * 16 + l16;
            ah[rt] = *(const bf16x8*)&AsH[ar * 40 + quad * 8];
            al[rt] = *(const bf16x8*)&AsL[ar * 40 + quad * 8];
        }
#pragma unroll
        for (int rt = 0; rt < 4; rt++)
#pragma unroll
            for (int ct = 0; ct < 2; ct++) {
                accg[rt][ct] = __builtin_amdgcn_mfma_f32_16x16x32_bf16(ah[rt], bh[ct], accg[rt][ct], 0, 0, 0);
                accg[rt][ct] = __builtin_amdgcn_mfma_f32_16x16x32_bf16(ah[rt], bl[ct], accg[rt][ct], 0, 0, 0);
                accg[rt][ct] = __builtin_amdgcn_mfma_f32_16x16x32_bf16(al[rt], bh[ct], accg[rt][ct], 0, 0, 0);
            }
    }
    // pa-GEMMs (K=64): accg += pa@(-PG), accp += pa@proxy. A from global (32 small loads,
    // paH/paL L2-hot, just written by k_scores). No LDS use -> no barrier needed.
    const bf16x8 zz = (bf16x8){0, 0, 0, 0, 0, 0, 0, 0};
#pragma unroll
    for (int kp = 0; kp < 2; kp++) {
        int kp0 = kp * 32;
        bf16x8 pah[4], pal[4];
#pragma unroll
        for (int rt = 0; rt < 4; rt++) {
            int ar = gr0 + wrow + rt * 16 + l16;
            if (ar < NNODE) {
                pah[rt] = *(const bf16x8*)&paH[(size_t)ar * NPROX + kp0 + quad * 8];
                pal[rt] = *(const bf16x8*)&paL[(size_t)ar * NPROX + kp0 + quad * 8];
            } else {
                pah[rt] = zz;
                pal[rt] = zz;
            }
        }
        bf16x8 pgh[2], pgl[2], prh[2], prl[2];
#pragma unroll
        for (int ct = 0; ct < 2; ct++) {
            int bc = cb0 + wcol + ct * 16 + l16;
            pgh[ct] = *(const bf16x8*)&pgTh[(size_t)bc * NPROX + kp0 + quad * 8];
            pgl[ct] = *(const bf16x8*)&pgTl[(size_t)bc * NPROX + kp0 + quad * 8];
            prh[ct] = *(const bf16x8*)&prTh[(size_t)bc * NPROX + kp0 + quad * 8];
            prl[ct] = *(const bf16x8*)&prTl[(size_t)bc * NPROX + kp0 + quad * 8];
        }
#pragma unroll
        for (int rt = 0; rt < 4; rt++)
#pragma unroll
            for (int ct = 0; ct < 2; ct++) {
                accg[rt][ct] = __builtin_amdgcn_mfma_f32_16x16x32_bf16(pah[rt], pgh[ct], accg[rt][ct], 0, 0, 0);
                accg[rt][ct] = __builtin_amdgcn_mfma_f32_16x16x32_bf16(pah[rt], pgl[ct], accg[rt][ct], 0, 0, 0);
                accg[rt][ct] = __builtin_amdgcn_mfma_f32_16x16x32_bf16(pal[rt], pgh[ct], accg[rt][ct], 0, 0, 0);
                accp[rt][ct] = __builtin_amdgcn_mfma_f32_16x16x32_bf16(pah[rt], prh[ct], accp[rt][ct], 0, 0, 0);
                accp[rt][ct] = __builtin_amdgcn_mfma_f32_16x16x32_bf16(pah[rt], prl[ct], accp[rt][ct], 0, 0, 0);
                accp[rt][ct] = __builtin_amdgcn_mfma_f32_16x16x32_bf16(pal[rt], prh[ct], accp[rt][ct], 0, 0, 0);
            }
    }
#pragma unroll
    for (int rt = 0; rt < 4; rt++) {
        int rbase = gr0 + wrow + rt * 16 + quad * 4;
#pragma unroll
        for (int reg = 0; reg < 4; reg++) {
            int row = rbase + reg;
            if (row >= NNODE) continue;
#pragma unroll
            for (int ct = 0; ct < 2; ct++) {
                int c = cb0 + wcol + ct * 16 + l16;
                float x = accg[rt][ct][reg] + bias[c];
                float g = 1.f / (1.f + __expf(-x));
                float o = outb[(size_t)row * F3 + c];
                float z = accp[rt][ct][reg];
                dout[(size_t)row * 768 + outoff + c] = o - (1.f - g) * z;
            }
        }
    }
}

// ---------------- launch ----------------
extern "C" void kernel_launch(void* const* d_in, const int* in_sizes, int n_in,
                              void* d_out, int out_size, void* d_ws, size_t ws_size,
                              hipStream_t stream) {
    const int* ent_adj = (const int*)d_in[0];
    const int* rel_adj = (const int*)d_in[1];
    const int* adj_list = (const int*)d_in[4];
    const int* r_index = (const int*)d_in[5];
    const float* r_val = (const float*)d_in[6];
    const float* ent_emb = (const float*)d_in[9];
    const float* rel_emb = (const float*)d_in[10];
    const float* e_attn = (const float*)d_in[11];
    const float* e_gate = (const float*)d_in[12];
    const float* e_proxy = (const float*)d_in[13];
    const float* e_bias = (const float*)d_in[14];
    const float* r_attn = (const float*)d_in[15];
    const float* r_gate = (const float*)d_in[16];
    const float* r_proxy = (const float*)d_in[17];
    const float* r_bias = (const float*)d_in[18];
    float* out = (float*)d_out;

    char* ws = (char*)d_ws;
    size_t off = 0;
    auto alloc = [&](size_t bytes) -> void* {
        off = (off + 255) & ~(size_t)255;
        void* p = ws + off;
        off += bytes;
        return p;
    };

    int* degcur = (int*)alloc(6 * NNODE * sizeof(int));
    int* degA = degcur, *curA = degcur + NNODE;
    int* degE = degcur + 2 * NNODE, *curE = degcur + 3 * NNODE;
    int* degR = degcur + 4 * NNODE, *curR = degcur + 5 * NNODE;
    int* offA = (int*)alloc((NNODE + 1) * sizeof(int));
    int* offE = (int*)alloc((NNODE + 1) * sizeof(int));
    int* offR = (int*)alloc((NNODE + 1) * sizeof(int));
    int2* ePackSc = (int2*)alloc(NTRI * sizeof(int2));
    int* eColE = (int*)alloc(NTRI * sizeof(int));
    int* eColR = (int*)alloc(NTRI * sizeof(int));
    float* nrm = (float*)alloc(NREL * sizeof(float));
    float2* attL0 = (float2*)alloc(NREL * sizeof(float2));
    float2* attL1 = (float2*)alloc(NREL * sizeof(float2));
    float* pnT_e = (float*)alloc((size_t)F3 * NPROX * sizeof(float));
    float* pnT_r = (float*)alloc((size_t)F3 * NPROX * sizeof(float));
    ushort_t* gTh_e = (ushort_t*)alloc((size_t)F3 * F3 * sizeof(ushort_t));
    ushort_t* gTl_e = (ushort_t*)alloc((size_t)F3 * F3 * sizeof(ushort_t));
    ushort_t* gTh_r = (ushort_t*)alloc((size_t)F3 * F3 * sizeof(ushort_t));
    ushort_t* gTl_r = (ushort_t*)alloc((size_t)F3 * F3 * sizeof(ushort_t));
    ushort_t* pgTh_e = (ushort_t*)alloc((size_t)F3 * NPROX * sizeof(ushort_t));
    ushort_t* pgTl_e = (ushort_t*)alloc((size_t)F3 * NPROX * sizeof(ushort_t));
    ushort_t* prTh_e = (ushort_t*)alloc((size_t)F3 * NPROX * sizeof(ushort_t));
    ushort_t* prTl_e = (ushort_t*)alloc((size_t)F3 * NPROX * sizeof(ushort_t));
    ushort_t* pgTh_r = (ushort_t*)alloc((size_t)F3 * NPROX * sizeof(ushort_t));
    ushort_t* pgTl_r = (ushort_t*)alloc((size_t)F3 * NPROX * sizeof(ushort_t));
    ushort_t* prTh_r = (ushort_t*)alloc((size_t)F3 * NPROX * sizeof(ushort_t));
    ushort_t* prTl_r = (ushort_t*)alloc((size_t)F3 * NPROX * sizeof(ushort_t));
    ushort_t* paH_e = (ushort_t*)alloc((size_t)NNODE * NPROX * sizeof(ushort_t));
    ushort_t* paL_e = (ushort_t*)alloc((size_t)NNODE * NPROX * sizeof(ushort_t));
    ushort_t* paH_r = (ushort_t*)alloc((size_t)NNODE * NPROX * sizeof(ushort_t));
    ushort_t* paL_r = (ushort_t*)alloc((size_t)NNODE * NPROX * sizeof(ushort_t));
    float* out_e = (float*)alloc((size_t)NNODE * F3 * sizeof(float));
    float* out_r = (float*)alloc((size_t)NNODE * F3 * sizeof(float));
    (void)ws_size; (void)in_sizes; (void)n_in; (void)out_size;

    hipMemsetAsync(degcur, 0, 6 * NNODE * sizeof(int), stream);

    int gT = (NTRI + 255) / 256;
    k_count3<<<gT, 256, 0, stream>>>(adj_list, ent_adj, rel_adj, degA, degE, degR);
    k_scan_fast<<<3, 1024, 0, stream>>>(degA, offA, degE, offE, degR, offR);
    k_relprep<<<NREL, 64, 0, stream>>>(rel_emb, e_attn, r_attn, nrm, attL0, attL1);
    k_place_sliced<<<gT * NSLICE, 256, 0, stream>>>(
        adj_list, adj_list + NTRI, ent_adj, ent_adj + NTRI, rel_adj, rel_adj + NTRI,
        r_index + NTRI, r_val, nrm, offA, offE, offR, curA, curE, curR,
        ePackSc, eColE, eColR);
    k_proxyprep2<<<2 * NPROX, 64, 0, stream>>>(e_proxy, r_proxy, pnT_e, pnT_r);
    k_gateprep2<<<2 * F3, F3, 0, stream>>>(e_gate, r_gate, gTh_e, gTl_e, gTh_r, gTl_r);
    k_pgprep<<<dim3(F3, 2), 64, 0, stream>>>(e_proxy, r_proxy, e_gate, r_gate,
                                             pgTh_e, pgTl_e, prTh_e, prTl_e,
                                             pgTh_r, pgTl_r, prTh_r, prTl_r);

    k_avg2<<<(2 * NNODE) / 4, 256, 0, stream>>>(offE, eColE, ent_emb, offR, eColR, rel_emb,
                                                out_e, out_r);

    int gW = NNODE / 4;
    k_agg2<<<gW, 256, 0, stream>>>(offA, ePackSc, attL0, rel_emb, out_e, out_r, 0);
    k_agg2<<<gW, 256, 0, stream>>>(offA, ePackSc, attL1, rel_emb, out_e, out_r, 1);

    dim3 gS(NNODE / 64, 1, 2);
    dim3 gG((NNODE + 127) / 128, F3 / 64, 2);
    k_scores<<<gS, 256, 0, stream>>>(out_e, out_r, pnT_e, pnT_r,
                                     paH_e, paL_e, paH_r, paL_r);
    k_gate_fused<<<gG, 256, 0, stream>>>(paH_e, paL_e, paH_r, paL_r,
                                         gTh_e, gTl_e, gTh_r, gTl_r,
                                         pgTh_e, pgTl_e, prTh_e, prTl_e,
                                         pgTh_r, pgTl_r, prTh_r, prTl_r,
                                         e_bias, r_bias, out_e, out_r, out);
}

// Round 5
// 935.189 us; speedup vs baseline: 1.1063x; 1.0148x over previous
//
#include <hip/hip_runtime.h>
#include <cmath>

#define NNODE 40000
#define NREL  2000
#define NTRI  600000
#define DIMK  128
#define F3    384
#define NPROX 64
#define EPSN  1e-12f
#define NSLICE 8
#define SLICE_ROWS (NNODE / NSLICE)
#define NRP 313  // row panels of 128 in k_gate_fused

typedef unsigned short ushort_t;
typedef __attribute__((ext_vector_type(8))) short bf16x8;
typedef __attribute__((ext_vector_type(4))) float f32x4;

static __device__ __forceinline__ float waveSum(float v) {
#pragma unroll
    for (int m = 32; m >= 1; m >>= 1) v += __shfl_xor(v, m, 64);
    return v;
}

static __device__ __forceinline__ void qreduce4(float4& v) {
#pragma unroll
    for (int m = 16; m <= 32; m <<= 1) {
        v.x += __shfl_xor(v.x, m, 64);
        v.y += __shfl_xor(v.y, m, 64);
        v.z += __shfl_xor(v.z, m, 64);
        v.w += __shfl_xor(v.w, m, 64);
    }
}

// pack two floats into hi-bf16 pair and lo-bf16 pair (truncation split, matches k_gateprep2)
static __device__ __forceinline__ uint2 splitpair(float x, float y) {
    unsigned int bx = __float_as_uint(x), by = __float_as_uint(y);
    unsigned int h = (bx >> 16) | (by & 0xffff0000u);
    float lx = x - __uint_as_float(bx & 0xffff0000u);
    float ly = y - __uint_as_float(by & 0xffff0000u);
    unsigned int l = (__float_as_uint(lx) >> 16) | (__float_as_uint(ly) & 0xffff0000u);
    return make_uint2(h, l);
}

static __device__ __forceinline__ void pack8(const float4& a, const float4& b,
                                             uint4& h, uint4& l) {
    uint2 p0 = splitpair(a.x, a.y);
    uint2 p1 = splitpair(a.z, a.w);
    uint2 p2 = splitpair(b.x, b.y);
    uint2 p3 = splitpair(b.z, b.w);
    h = make_uint4(p0.x, p1.x, p2.x, p3.x);
    l = make_uint4(p0.y, p1.y, p2.y, p3.y);
}

// ---------------- CSR build ----------------
__global__ void k_count3(const int* __restrict__ rA, const int* __restrict__ rE,
                         const int* __restrict__ rR, int* __restrict__ dA,
                         int* __restrict__ dE, int* __restrict__ dR) {
    int t = blockIdx.x * 256 + threadIdx.x;
    if (t < NTRI) {
        atomicAdd(&dA[rA[t]], 1);
        atomicAdd(&dE[rE[t]], 1);
        atomicAdd(&dR[rR[t]], 1);
    }
}

__global__ void k_scan_fast(const int* __restrict__ dA, int* __restrict__ oA,
                            const int* __restrict__ dE, int* __restrict__ oE,
                            const int* __restrict__ dR, int* __restrict__ oR) {
    const int* deg = blockIdx.x == 0 ? dA : (blockIdx.x == 1 ? dE : dR);
    int* off = blockIdx.x == 0 ? oA : (blockIdx.x == 1 ? oE : oR);
    __shared__ int wsum[16];
    __shared__ int wpre[16];
    int tid = threadIdx.x;
    int lane = tid & 63, wv = tid >> 6;
    const int CH = 40;
    int base = tid * CH;
    int s = 0;
    for (int i = 0; i < CH; i++) {
        int idx = base + i;
        s += (idx < NNODE) ? deg[idx] : 0;
    }
    int incl = s;
#pragma unroll
    for (int m = 1; m < 64; m <<= 1) {
        int v = __shfl_up(incl, m, 64);
        if (lane >= m) incl += v;
    }
    if (lane == 63) wsum[wv] = incl;
    __syncthreads();
    if (tid < 16) {
        int v = wsum[tid];
#pragma unroll
        for (int m = 1; m < 16; m <<= 1) {
            int u = __shfl_up(v, m, 64);
            if (tid >= m) v += u;
        }
        wpre[tid] = v;
    }
    __syncthreads();
    int waveoff = (wv == 0) ? 0 : wpre[wv - 1];
    int run = waveoff + incl - s;
    for (int i = 0; i < CH; i++) {
        int idx = base + i;
        if (idx < NNODE) {
            off[idx] = run;
            run += deg[idx];
        }
    }
    if (tid == 0) off[NNODE] = wpre[15];
}

// XCD-sliced payload placement: slice = blockIdx&7 (round-robin XCD heuristic).
__global__ __launch_bounds__(256) void k_place_sliced(
    const int* __restrict__ rA, const int* __restrict__ cA,
    const int* __restrict__ rE, const int* __restrict__ cE,
    const int* __restrict__ rR, const int* __restrict__ cR,
    const int* __restrict__ ridx, const float* __restrict__ rval,
    const float* __restrict__ nrm,
    const int* __restrict__ oA, const int* __restrict__ oE, const int* __restrict__ oR,
    int* __restrict__ cntA, int* __restrict__ cntE, int* __restrict__ cntR,
    int2* __restrict__ ePackSc, int* __restrict__ eColE, int* __restrict__ eColR) {
    int slice = blockIdx.x & (NSLICE - 1);
    int t = (blockIdx.x >> 3) * 256 + threadIdx.x;
    if (t >= NTRI) return;
    int lo = slice * SLICE_ROWS;
    int r = rA[t];
    if ((unsigned)(r - lo) < (unsigned)SLICE_ROWS) {
        int rid = ridx[t];
        float v = rval[t];
        float sc = v / fmaxf(fabsf(v) * nrm[rid], EPSN);
        int p = oA[r] + atomicAdd(&cntA[r], 1);
        ePackSc[p] = make_int2(cA[t] | (rid << 16), __float_as_int(sc));
    }
    r = rE[t];
    if ((unsigned)(r - lo) < (unsigned)SLICE_ROWS)
        eColE[oE[r] + atomicAdd(&cntE[r], 1)] = cE[t];
    r = rR[t];
    if ((unsigned)(r - lo) < (unsigned)SLICE_ROWS)
        eColR[oR[r] + atomicAdd(&cntR[r], 1)] = cR[t];
}

// ---------------- small precomputes ----------------
__global__ void k_relprep(const float* __restrict__ rel_emb,
                          const float* __restrict__ e_attn, const float* __restrict__ r_attn,
                          float* __restrict__ nrm, float2* __restrict__ attL0,
                          float2* __restrict__ attL1) {
    int r = blockIdx.x;
    int lane = threadIdx.x;
    float a = rel_emb[r * DIMK + lane];
    float b = rel_emb[r * DIMK + 64 + lane];
    float nn = waveSum(a * a + b * b);
    float d0 = waveSum(a * e_attn[lane] + b * e_attn[64 + lane]);
    float d1 = waveSum(a * e_attn[DIMK + lane] + b * e_attn[DIMK + 64 + lane]);
    float d2 = waveSum(a * r_attn[lane] + b * r_attn[64 + lane]);
    float d3 = waveSum(a * r_attn[DIMK + lane] + b * r_attn[DIMK + 64 + lane]);
    if (lane == 0) {
        nrm[r] = sqrtf(nn);
        attL0[r] = make_float2(d0, d2);
        attL1[r] = make_float2(d1, d3);
    }
}

// both encoders' proxy prep in one dispatch (normalized proxies, [k][64] layout for k_scores)
__global__ void k_proxyprep2(const float* __restrict__ e_proxy, const float* __restrict__ r_proxy,
                             float* __restrict__ pnT_e, float* __restrict__ pnT_r) {
    int enc = blockIdx.x >= NPROX;
    int k = blockIdx.x & (NPROX - 1);
    const float* proxy = enc ? r_proxy : e_proxy;
    float* pnT = enc ? pnT_r : pnT_e;
    int lane = threadIdx.x;
    float v[6];
    float ss = 0.f;
#pragma unroll
    for (int j = 0; j < 6; j++) {
        v[j] = proxy[k * F3 + j * 64 + lane];
        ss += v[j] * v[j];
    }
    ss = waveSum(ss);
    float inv = 1.0f / fmaxf(sqrtf(ss), EPSN);
#pragma unroll
    for (int j = 0; j < 6; j++) pnT[(j * 64 + lane) * NPROX + k] = v[j] * inv;
}

// both encoders' gate prep in one dispatch: gT[c][k] bf16 hi/lo split
__global__ void k_gateprep2(const float* __restrict__ e_gate, const float* __restrict__ r_gate,
                            ushort_t* __restrict__ the, ushort_t* __restrict__ tle,
                            ushort_t* __restrict__ thr, ushort_t* __restrict__ tlr) {
    int enc = blockIdx.x >= F3;
    int k = enc ? blockIdx.x - F3 : blockIdx.x;
    const float* g = enc ? r_gate : e_gate;
    ushort_t* th = enc ? thr : the;
    ushort_t* tl = enc ? tlr : tle;
    int c = threadIdx.x;
    float v = g[(size_t)k * F3 + c];
    unsigned int b = __float_as_uint(v);
    th[(size_t)c * F3 + k] = (ushort_t)(b >> 16);
    float lo = v - __uint_as_float(b & 0xffff0000u);
    tl[(size_t)c * F3 + k] = (ushort_t)(__float_as_uint(lo) >> 16);
}

// PG = proxy @ gate (negated, for fused gate input) and proxyT, both bf16 hi/lo split,
// [c][p] layout (B-operand fragment layout for the K=64 pa-GEMMs).
__global__ void k_pgprep(const float* __restrict__ e_proxy, const float* __restrict__ r_proxy,
                         const float* __restrict__ e_gate, const float* __restrict__ r_gate,
                         ushort_t* __restrict__ pgTh_e, ushort_t* __restrict__ pgTl_e,
                         ushort_t* __restrict__ prTh_e, ushort_t* __restrict__ prTl_e,
                         ushort_t* __restrict__ pgTh_r, ushort_t* __restrict__ pgTl_r,
                         ushort_t* __restrict__ prTh_r, ushort_t* __restrict__ prTl_r) {
    int enc = blockIdx.y;
    const float* proxy = enc ? r_proxy : e_proxy;
    const float* gate = enc ? r_gate : e_gate;
    ushort_t* pgTh = enc ? pgTh_r : pgTh_e;
    ushort_t* pgTl = enc ? pgTl_r : pgTl_e;
    ushort_t* prTh = enc ? prTh_r : prTh_e;
    ushort_t* prTl = enc ? prTl_r : prTl_e;
    int c = blockIdx.x;
    int p = threadIdx.x;  // 64 threads
    float s = 0.f;
    for (int k = 0; k < F3; k++) s = fmaf(proxy[p * F3 + k], gate[(size_t)k * F3 + c], s);
    float v = -s;  // NEGATED: gate accumulator adds pa@(-PG)
    unsigned int b = __float_as_uint(v);
    pgTh[c * NPROX + p] = (ushort_t)(b >> 16);
    float lo = v - __uint_as_float(b & 0xffff0000u);
    pgTl[c * NPROX + p] = (ushort_t)(__float_as_uint(lo) >> 16);
    float pv = proxy[p * F3 + c];
    unsigned int pb = __float_as_uint(pv);
    prTh[c * NPROX + p] = (ushort_t)(pb >> 16);
    float plo = pv - __uint_as_float(pb & 0xffff0000u);
    prTl[c * NPROX + p] = (ushort_t)(__float_as_uint(plo) >> 16);
}

// ---------------- fused neighbor mean + tanh ----------------
__global__ __launch_bounds__(256) void k_avg2(
    const int* __restrict__ offE, const int* __restrict__ eColE, const float* __restrict__ ent_emb,
    const int* __restrict__ offR, const int* __restrict__ eColR, const float* __restrict__ rel_emb,
    float* __restrict__ out_e, float* __restrict__ out_r) {
    int gw = (blockIdx.x * blockDim.x + threadIdx.x) >> 6;
    int lane = threadIdx.x & 63;
    if (gw >= 2 * NNODE) return;
    bool isR = gw >= NNODE;
    int wid = isR ? gw - NNODE : gw;
    const int* off = isR ? offR : offE;
    const int* ecol = isR ? eColR : eColE;
    const float4* emb4 = (const float4*)(isR ? rel_emb : ent_emb);
    float* outp = isR ? out_r : out_e;
    int q = lane >> 4, ql = lane & 15;
    int e0 = off[wid], e1 = off[wid + 1];
    float4 aA = {0, 0, 0, 0}, aB = {0, 0, 0, 0};
    for (int base = e0; base < e1; base += 64) {
        int n = min(64, e1 - base);
        int mc = (lane < n) ? ecol[base + lane] : -1;
        for (int j = 0; j < n; j += 4) {
            int e = j + q;
            int c = __shfl(mc, e, 64);
            if (e < n) {
                float4 va = emb4[(size_t)c * 32 + ql];
                float4 vb = emb4[(size_t)c * 32 + 16 + ql];
                aA.x += va.x; aA.y += va.y; aA.z += va.z; aA.w += va.w;
                aB.x += vb.x; aB.y += vb.y; aB.z += vb.z; aB.w += vb.w;
            }
        }
    }
    qreduce4(aA);
    qreduce4(aB);
    if (q == 0) {
        float invd = (e1 > e0) ? 1.0f / (float)(e1 - e0) : 0.0f;
        float4* o = (float4*)outp;
        float4 ra = {tanhf(aA.x * invd), tanhf(aA.y * invd), tanhf(aA.z * invd), tanhf(aA.w * invd)};
        float4 rb = {tanhf(aB.x * invd), tanhf(aB.y * invd), tanhf(aB.z * invd), tanhf(aB.w * invd)};
        o[(size_t)wid * 96 + ql] = ra;
        o[(size_t)wid * 96 + 16 + ql] = rb;
    }
}

// ---------------- fused reflection attention aggregation ----------------
__global__ __launch_bounds__(256) void k_agg2(
    const int* __restrict__ off, const int2* __restrict__ ePackSc,
    const float2* __restrict__ attL, const float* __restrict__ rel_emb,
    float* __restrict__ out_e, float* __restrict__ out_r, int lin) {
    int wid = (blockIdx.x * blockDim.x + threadIdx.x) >> 6;
    int lane = threadIdx.x & 63;
    if (wid >= NNODE) return;
    int q = lane >> 4, ql = lane & 15;
    int e0 = off[wid], e1 = off[wid + 1];
    const float4* rel4 = (const float4*)rel_emb;
    const float4* pe4 = (const float4*)out_e;
    const float4* pr4 = (const float4*)out_r;
    int sA = lin * 32 + ql, sB = lin * 32 + 16 + ql;
    float4 aEa = {0, 0, 0, 0}, aEb = {0, 0, 0, 0}, aRa = {0, 0, 0, 0}, aRb = {0, 0, 0, 0};
    float sE = 0.f, sR = 0.f;
    for (int base = e0; base < e1; base += 64) {
        int n = min(64, e1 - base);
        int pk = 0;
        float sc = 0.f, wE = 0.f, wR = 0.f;
        if (lane < n) {
            int2 ps = ePackSc[base + lane];
            pk = ps.x;
            sc = __int_as_float(ps.y);
            float2 a = attL[pk >> 16];
            wE = __expf(sc * a.x);
            wR = __expf(sc * a.y);
        }
        for (int j = 0; j < n; j += 4) {
            int e = j + q;
            int pke = __shfl(pk, e, 64);
            float sce = __shfl(sc, e, 64);
            float wEe = __shfl(wE, e, 64);
            float wRe = __shfl(wR, e, 64);
            int c = pke & 0xFFFF;
            int r = pke >> 16;
            float4 ra = rel4[(size_t)r * 32 + ql];
            float4 rb = rel4[(size_t)r * 32 + 16 + ql];
            float4 fa = pe4[(size_t)c * 96 + sA];
            float4 fb = pe4[(size_t)c * 96 + sB];
            float4 ga = pr4[(size_t)c * 96 + sA];
            float4 gb = pr4[(size_t)c * 96 + sB];
            float tax = sce * ra.x, tay = sce * ra.y, taz = sce * ra.z, taw = sce * ra.w;
            float tbx = sce * rb.x, tby = sce * rb.y, tbz = sce * rb.z, tbw = sce * rb.w;
            float dE = fa.x * tax + fa.y * tay + fa.z * taz + fa.w * taw +
                       fb.x * tbx + fb.y * tby + fb.z * tbz + fb.w * tbw;
            float dR = ga.x * tax + ga.y * tay + ga.z * taz + ga.w * taw +
                       gb.x * tbx + gb.y * tby + gb.z * tbz + gb.w * tbw;
#pragma unroll
            for (int m = 1; m <= 8; m <<= 1) {
                dE += __shfl_xor(dE, m, 64);
                dR += __shfl_xor(dR, m, 64);
            }
            dE *= 2.f;
            dR *= 2.f;
            aEa.x += wEe * (fa.x - dE * tax);
            aEa.y += wEe * (fa.y - dE * tay);
            aEa.z += wEe * (fa.z - dE * taz);
            aEa.w += wEe * (fa.w - dE * taw);
            aEb.x += wEe * (fb.x - dE * tbx);
            aEb.y += wEe * (fb.y - dE * tby);
            aEb.z += wEe * (fb.z - dE * tbz);
            aEb.w += wEe * (fb.w - dE * tbw);
            aRa.x += wRe * (ga.x - dR * tax);
            aRa.y += wRe * (ga.y - dR * tay);
            aRa.z += wRe * (ga.z - dR * taz);
            aRa.w += wRe * (ga.w - dR * taw);
            aRb.x += wRe * (gb.x - dR * tbx);
            aRb.y += wRe * (gb.y - dR * tby);
            aRb.z += wRe * (gb.z - dR * tbz);
            aRb.w += wRe * (gb.w - dR * tbw);
            sE += wEe;
            sR += wRe;
        }
    }
    qreduce4(aEa);
    qreduce4(aEb);
    qreduce4(aRa);
    qreduce4(aRb);
#pragma unroll
    for (int m = 16; m <= 32; m <<= 1) {
        sE += __shfl_xor(sE, m, 64);
        sR += __shfl_xor(sR, m, 64);
    }
    if (q == 0) {
        float iE = (e1 > e0) ? 1.f / sE : 0.f;
        float4* o = (float4*)out_e;
        float4 wa = {tanhf(aEa.x * iE), tanhf(aEa.y * iE), tanhf(aEa.z * iE), tanhf(aEa.w * iE)};
        float4 wb = {tanhf(aEb.x * iE), tanhf(aEb.y * iE), tanhf(aEb.z * iE), tanhf(aEb.w * iE)};
        o[(size_t)wid * 96 + (lin + 1) * 32 + ql] = wa;
        o[(size_t)wid * 96 + (lin + 1) * 32 + 16 + ql] = wb;
    } else if (q == 1) {
        float iR = (e1 > e0) ? 1.f / sR : 0.f;
        float4* o = (float4*)out_r;
        float4 wa = {tanhf(aRa.x * iR), tanhf(aRa.y * iR), tanhf(aRa.z * iR), tanhf(aRa.w * iR)};
        float4 wb = {tanhf(aRb.x * iR), tanhf(aRb.y * iR), tanhf(aRb.z * iR), tanhf(aRb.w * iR)};
        o[(size_t)wid * 96 + (lin + 1) * 32 + ql] = wa;
        o[(size_t)wid * 96 + (lin + 1) * 32 + 16 + ql] = wb;
    }
}

// ---------------- epilogue (z = encoder) ----------------
// proxy-attention scores + softmax; emits pa in bf16 hi/lo split (MFMA A-operand form)
__global__ void k_scores(const float* __restrict__ out_e, const float* __restrict__ out_r,
                         const float* __restrict__ pnT_e, const float* __restrict__ pnT_r,
                         ushort_t* __restrict__ paH_e, ushort_t* __restrict__ paL_e,
                         ushort_t* __restrict__ paH_r, ushort_t* __restrict__ paL_r) {
    const float* outb = blockIdx.z ? out_r : out_e;
    const float* pnT = blockIdx.z ? pnT_r : pnT_e;
    ushort_t* paH = blockIdx.z ? paH_r : paH_e;
    ushort_t* paL = blockIdx.z ? paL_r : paL_e;
    __shared__ __align__(16) float As[16][68];
    __shared__ __align__(16) float Bs[16][68];
    __shared__ float Ss[64][65];
    __shared__ float rnS[64];
    int tid = threadIdx.x;
    int row0 = blockIdx.x * 64;
    int kk = tid & 15, rr = tid >> 4;
    int cb = tid & 63, kb = tid >> 6;
    int tx = tid & 15, ty = tid >> 4;
    int c0 = tx * 4, r0 = ty * 4;
    float acc[4][4] = {};
    float ssp[4] = {};
    for (int k0 = 0; k0 < F3; k0 += 16) {
#pragma unroll
        for (int u = 0; u < 4; u++) {
            int r = rr + u * 16;
            float v = outb[(size_t)(row0 + r) * F3 + k0 + kk];
            As[kk][r] = v;
            ssp[u] += v * v;
        }
#pragma unroll
        for (int u = 0; u < 4; u++) {
            int k = kb + u * 4;
            Bs[k][cb] = pnT[(size_t)(k0 + k) * NPROX + cb];
        }
        __syncthreads();
#pragma unroll
        for (int k = 0; k < 16; k++) {
            float4 av = *(const float4*)&As[k][r0];
            float4 bv = *(const float4*)&Bs[k][c0];
            float a[4] = {av.x, av.y, av.z, av.w};
            float b[4] = {bv.x, bv.y, bv.z, bv.w};
#pragma unroll
            for (int i = 0; i < 4; i++)
#pragma unroll
                for (int j = 0; j < 4; j++) acc[i][j] += a[i] * b[j];
        }
        __syncthreads();
    }
#pragma unroll
    for (int u = 0; u < 4; u++) {
        float ss = ssp[u];
#pragma unroll
        for (int m = 1; m < 16; m <<= 1) ss += __shfl_xor(ss, m, 64);
        if (kk == 0) rnS[rr + u * 16] = 1.0f / fmaxf(sqrtf(ss), EPSN);
    }
    __syncthreads();
#pragma unroll
    for (int i = 0; i < 4; i++) {
        float rn = rnS[r0 + i];
#pragma unroll
        for (int j = 0; j < 4; j++) Ss[r0 + i][c0 + j] = acc[i][j] * rn;
    }
    __syncthreads();
    if (tid < 64) {
        int r = tid;
        float m = -1e30f;
        for (int c = 0; c < 64; c++) m = fmaxf(m, Ss[r][c]);
        float s = 0.f;
        for (int c = 0; c < 64; c++) s += expf(Ss[r][c] - m);
        float inv = 1.f / s;
        size_t base = (size_t)(row0 + r) * NPROX;
        for (int c = 0; c < 64; c++) {
            float v = expf(Ss[r][c] - m) * inv;
            unsigned int b = __float_as_uint(v);
            paH[base + c] = (ushort_t)(b >> 16);
            float lo = v - __uint_as_float(b & 0xffff0000u);
            paL[base + c] = (ushort_t)(__float_as_uint(lo) >> 16);
        }
    }
}

// Fused gate+pf kernel with XCD-ganged block mapping.
// R4 counters: FETCH 486 MB (vs 302 pre-fusion) -- the 6 col-tiles x 2 encoders
// re-stream the same A row-panels from HBM because linear dispatch puts sharers
// on different XCDs (non-shared L2s). Remap: id -> xcd=id&7, q=(id>>3)/12,
// v=(id>>3)%12; rp=xcd+8q (row panel), ct=v>>1 (col tile), z=v&1 (encoder).
// All 12 sharers of a 196 KB A-panel run consecutively on ONE XCD -> 11/12
// reads become L2 hits. Inner kernel unchanged from R4.
__global__ __launch_bounds__(256) void k_gate_fused(
    const ushort_t* __restrict__ paH_e, const ushort_t* __restrict__ paL_e,
    const ushort_t* __restrict__ paH_r, const ushort_t* __restrict__ paL_r,
    const ushort_t* __restrict__ gTh_e, const ushort_t* __restrict__ gTl_e,
    const ushort_t* __restrict__ gTh_r, const ushort_t* __restrict__ gTl_r,
    const ushort_t* __restrict__ pgTh_e, const ushort_t* __restrict__ pgTl_e,
    const ushort_t* __restrict__ prTh_e, const ushort_t* __restrict__ prTl_e,
    const ushort_t* __restrict__ pgTh_r, const ushort_t* __restrict__ pgTl_r,
    const ushort_t* __restrict__ prTh_r, const ushort_t* __restrict__ prTl_r,
    const float* __restrict__ e_bias, const float* __restrict__ r_bias,
    const float* __restrict__ out_e, const float* __restrict__ out_r,
    float* __restrict__ dout) {
    int id = blockIdx.x;
    int slot = id >> 3;
    int rp = (id & 7) + (slot / 12) * 8;
    int v = slot % 12;
    int ctile = v >> 1;
    int z = v & 1;
    if (rp >= NRP) return;  // uniform early-exit, before any barrier
    const ushort_t* paH = z ? paH_r : paH_e;
    const ushort_t* paL = z ? paL_r : paL_e;
    const ushort_t* gTh = z ? gTh_r : gTh_e;
    const ushort_t* gTl = z ? gTl_r : gTl_e;
    const ushort_t* pgTh = z ? pgTh_r : pgTh_e;
    const ushort_t* pgTl = z ? pgTl_r : pgTl_e;
    const ushort_t* prTh = z ? prTh_r : prTh_e;
    const ushort_t* prTl = z ? prTl_r : prTl_e;
    const float* bias = z ? r_bias : e_bias;
    const float* outb = z ? out_r : out_e;
    int outoff = z ? F3 : 0;
    __shared__ __align__(16) ushort_t AsH[128 * 40];
    __shared__ __align__(16) ushort_t AsL[128 * 40];
    int tid = threadIdx.x;
    int w = tid >> 6, lane = tid & 63;
    int quad = lane >> 4, l16 = lane & 15;
    int wrow = (w >> 1) * 64, wcol = (w & 1) * 32;
    int gr0 = rp * 128;
    int cb0 = ctile * 64;
    f32x4 accg[4][2], accp[4][2];
#pragma unroll
    for (int rt = 0; rt < 4; rt++)
#pragma unroll
        for (int ct = 0; ct < 2; ct++) {
            accg[rt][ct] = (f32x4){0.f, 0.f, 0.f, 0.f};
            accp[rt][ct] = (f32x4){0.f, 0.f, 0.f, 0.f};
        }

    int srow = tid >> 2, sseg = tid & 3;
    int gr_u0 = gr0 + srow;
    int gr_u1 = gr0 + srow + 64;
    float4 p0a, p0b, p1a, p1b;
    {
        float4 zv = {0, 0, 0, 0};
        p0a = p0b = p1a = p1b = zv;
        if (gr_u0 < NNODE) {
            p0a = *(const float4*)&outb[(size_t)gr_u0 * F3 + sseg * 8];
            p0b = *(const float4*)&outb[(size_t)gr_u0 * F3 + sseg * 8 + 4];
        }
        if (gr_u1 < NNODE) {
            p1a = *(const float4*)&outb[(size_t)gr_u1 * F3 + sseg * 8];
            p1b = *(const float4*)&outb[(size_t)gr_u1 * F3 + sseg * 8 + 4];
        }
    }
    for (int k0 = 0; k0 < F3; k0 += 32) {
        __syncthreads();  // previous step's consumers done with LDS
        uint4 h0, l0, h1, l1;
        pack8(p0a, p0b, h0, l0);
        pack8(p1a, p1b, h1, l1);
        *(uint4*)&AsH[srow * 40 + sseg * 8] = h0;
        *(uint4*)&AsL[srow * 40 + sseg * 8] = l0;
        *(uint4*)&AsH[(srow + 64) * 40 + sseg * 8] = h1;
        *(uint4*)&AsL[(srow + 64) * 40 + sseg * 8] = l1;
        // B loads for CURRENT step (L2-hot)
        bf16x8 bh[2], bl[2];
#pragma unroll
        for (int ct = 0; ct < 2; ct++) {
            int bc = cb0 + wcol + ct * 16 + l16;
            bh[ct] = *(const bf16x8*)&gTh[(size_t)bc * F3 + k0 + quad * 8];
            bl[ct] = *(const bf16x8*)&gTl[(size_t)bc * F3 + k0 + quad * 8];
        }
        // prefetch A panel (f32) for NEXT step
        int kn = k0 + 32;
        if (kn < F3) {
            if (gr_u0 < NNODE) {
                p0a = *(const float4*)&outb[(size_t)gr_u0 * F3 + kn + sseg * 8];
                p0b = *(const float4*)&outb[(size_t)gr_u0 * F3 + kn + sseg * 8 + 4];
            }
            if (gr_u1 < NNODE) {
                p1a = *(const float4*)&outb[(size_t)gr_u1 * F3 + kn + sseg * 8];
                p1b = *(const float4*)&outb[(size_t)gr_u1 * F3 + kn + sseg * 8 + 4];
            }
        }
        __syncthreads();  // staged A visible
        bf16x8 ah[4], al[4];
#pragma unroll
        for (int rt = 0; rt < 4; rt++) {
            int ar = wrow + rt * 16 + l16;
            ah[rt] = *(const bf16x8*)&AsH[ar * 40 + quad * 8];
            al[rt] = *(const bf16x8*)&AsL[ar * 40 + quad * 8];
        }
#pragma unroll
        for (int rt = 0; rt < 4; rt++)
#pragma unroll
            for (int ct = 0; ct < 2; ct++) {
                accg[rt][ct] = __builtin_amdgcn_mfma_f32_16x16x32_bf16(ah[rt], bh[ct], accg[rt][ct], 0, 0, 0);
                accg[rt][ct] = __builtin_amdgcn_mfma_f32_16x16x32_bf16(ah[rt], bl[ct], accg[rt][ct], 0, 0, 0);
                accg[rt][ct] = __builtin_amdgcn_mfma_f32_16x16x32_bf16(al[rt], bh[ct], accg[rt][ct], 0, 0, 0);
            }
    }
    // pa-GEMMs (K=64): accg += pa@(-PG), accp += pa@proxy.
    const bf16x8 zz = (bf16x8){0, 0, 0, 0, 0, 0, 0, 0};
#pragma unroll
    for (int kp = 0; kp < 2; kp++) {
        int kp0 = kp * 32;
        bf16x8 pah[4], pal[4];
#pragma unroll
        for (int rt = 0; rt < 4; rt++) {
            int ar = gr0 + wrow + rt * 16 + l16;
            if (ar < NNODE) {
                pah[rt] = *(const bf16x8*)&paH[(size_t)ar * NPROX + kp0 + quad * 8];
                pal[rt] = *(const bf16x8*)&paL[(size_t)ar * NPROX + kp0 + quad * 8];
            } else {
                pah[rt] = zz;
                pal[rt] = zz;
            }
        }
        bf16x8 pgh[2], pgl[2], prh[2], prl[2];
#pragma unroll
        for (int ct = 0; ct < 2; ct++) {
            int bc = cb0 + wcol + ct * 16 + l16;
            pgh[ct] = *(const bf16x8*)&pgTh[(size_t)bc * NPROX + kp0 + quad * 8];
            pgl[ct] = *(const bf16x8*)&pgTl[(size_t)bc * NPROX + kp0 + quad * 8];
            prh[ct] = *(const bf16x8*)&prTh[(size_t)bc * NPROX + kp0 + quad * 8];
            prl[ct] = *(const bf16x8*)&prTl[(size_t)bc * NPROX + kp0 + quad * 8];
        }
#pragma unroll
        for (int rt = 0; rt < 4; rt++)
#pragma unroll
            for (int ct = 0; ct < 2; ct++) {
                accg[rt][ct] = __builtin_amdgcn_mfma_f32_16x16x32_bf16(pah[rt], pgh[ct], accg[rt][ct], 0, 0, 0);
                accg[rt][ct] = __builtin_amdgcn_mfma_f32_16x16x32_bf16(pah[rt], pgl[ct], accg[rt][ct], 0, 0, 0);
                accg[rt][ct] = __builtin_amdgcn_mfma_f32_16x16x32_bf16(pal[rt], pgh[ct], accg[rt][ct], 0, 0, 0);
                accp[rt][ct] = __builtin_amdgcn_mfma_f32_16x16x32_bf16(pah[rt], prh[ct], accp[rt][ct], 0, 0, 0);
                accp[rt][ct] = __builtin_amdgcn_mfma_f32_16x16x32_bf16(pah[rt], prl[ct], accp[rt][ct], 0, 0, 0);
                accp[rt][ct] = __builtin_amdgcn_mfma_f32_16x16x32_bf16(pal[rt], prh[ct], accp[rt][ct], 0, 0, 0);
            }
    }
#pragma unroll
    for (int rt = 0; rt < 4; rt++) {
        int rbase = gr0 + wrow + rt * 16 + quad * 4;
#pragma unroll
        for (int reg = 0; reg < 4; reg++) {
            int row = rbase + reg;
            if (row >= NNODE) continue;
#pragma unroll
            for (int ct = 0; ct < 2; ct++) {
                int c = cb0 + wcol + ct * 16 + l16;
                float x = accg[rt][ct][reg] + bias[c];
                float g = 1.f / (1.f + __expf(-x));
                float o = outb[(size_t)row * F3 + c];
                float zp = accp[rt][ct][reg];
                dout[(size_t)row * 768 + outoff + c] = o - (1.f - g) * zp;
            }
        }
    }
}

// ---------------- launch ----------------
extern "C" void kernel_launch(void* const* d_in, const int* in_sizes, int n_in,
                              void* d_out, int out_size, void* d_ws, size_t ws_size,
                              hipStream_t stream) {
    const int* ent_adj = (const int*)d_in[0];
    const int* rel_adj = (const int*)d_in[1];
    const int* adj_list = (const int*)d_in[4];
    const int* r_index = (const int*)d_in[5];
    const float* r_val = (const float*)d_in[6];
    const float* ent_emb = (const float*)d_in[9];
    const float* rel_emb = (const float*)d_in[10];
    const float* e_attn = (const float*)d_in[11];
    const float* e_gate = (const float*)d_in[12];
    const float* e_proxy = (const float*)d_in[13];
    const float* e_bias = (const float*)d_in[14];
    const float* r_attn = (const float*)d_in[15];
    const float* r_gate = (const float*)d_in[16];
    const float* r_proxy = (const float*)d_in[17];
    const float* r_bias = (const float*)d_in[18];
    float* out = (float*)d_out;

    char* ws = (char*)d_ws;
    size_t off = 0;
    auto alloc = [&](size_t bytes) -> void* {
        off = (off + 255) & ~(size_t)255;
        void* p = ws + off;
        off += bytes;
        return p;
    };

    int* degcur = (int*)alloc(6 * NNODE * sizeof(int));
    int* degA = degcur, *curA = degcur + NNODE;
    int* degE = degcur + 2 * NNODE, *curE = degcur + 3 * NNODE;
    int* degR = degcur + 4 * NNODE, *curR = degcur + 5 * NNODE;
    int* offA = (int*)alloc((NNODE + 1) * sizeof(int));
    int* offE = (int*)alloc((NNODE + 1) * sizeof(int));
    int* offR = (int*)alloc((NNODE + 1) * sizeof(int));
    int2* ePackSc = (int2*)alloc(NTRI * sizeof(int2));
    int* eColE = (int*)alloc(NTRI * sizeof(int));
    int* eColR = (int*)alloc(NTRI * sizeof(int));
    float* nrm = (float*)alloc(NREL * sizeof(float));
    float2* attL0 = (float2*)alloc(NREL * sizeof(float2));
    float2* attL1 = (float2*)alloc(NREL * sizeof(float2));
    float* pnT_e = (float*)alloc((size_t)F3 * NPROX * sizeof(float));
    float* pnT_r = (float*)alloc((size_t)F3 * NPROX * sizeof(float));
    ushort_t* gTh_e = (ushort_t*)alloc((size_t)F3 * F3 * sizeof(ushort_t));
    ushort_t* gTl_e = (ushort_t*)alloc((size_t)F3 * F3 * sizeof(ushort_t));
    ushort_t* gTh_r = (ushort_t*)alloc((size_t)F3 * F3 * sizeof(ushort_t));
    ushort_t* gTl_r = (ushort_t*)alloc((size_t)F3 * F3 * sizeof(ushort_t));
    ushort_t* pgTh_e = (ushort_t*)alloc((size_t)F3 * NPROX * sizeof(ushort_t));
    ushort_t* pgTl_e = (ushort_t*)alloc((size_t)F3 * NPROX * sizeof(ushort_t));
    ushort_t* prTh_e = (ushort_t*)alloc((size_t)F3 * NPROX * sizeof(ushort_t));
    ushort_t* prTl_e = (ushort_t*)alloc((size_t)F3 * NPROX * sizeof(ushort_t));
    ushort_t* pgTh_r = (ushort_t*)alloc((size_t)F3 * NPROX * sizeof(ushort_t));
    ushort_t* pgTl_r = (ushort_t*)alloc((size_t)F3 * NPROX * sizeof(ushort_t));
    ushort_t* prTh_r = (ushort_t*)alloc((size_t)F3 * NPROX * sizeof(ushort_t));
    ushort_t* prTl_r = (ushort_t*)alloc((size_t)F3 * NPROX * sizeof(ushort_t));
    ushort_t* paH_e = (ushort_t*)alloc((size_t)NNODE * NPROX * sizeof(ushort_t));
    ushort_t* paL_e = (ushort_t*)alloc((size_t)NNODE * NPROX * sizeof(ushort_t));
    ushort_t* paH_r = (ushort_t*)alloc((size_t)NNODE * NPROX * sizeof(ushort_t));
    ushort_t* paL_r = (ushort_t*)alloc((size_t)NNODE * NPROX * sizeof(ushort_t));
    float* out_e = (float*)alloc((size_t)NNODE * F3 * sizeof(float));
    float* out_r = (float*)alloc((size_t)NNODE * F3 * sizeof(float));
    (void)ws_size; (void)in_sizes; (void)n_in; (void)out_size;

    hipMemsetAsync(degcur, 0, 6 * NNODE * sizeof(int), stream);

    int gT = (NTRI + 255) / 256;
    k_count3<<<gT, 256, 0, stream>>>(adj_list, ent_adj, rel_adj, degA, degE, degR);
    k_scan_fast<<<3, 1024, 0, stream>>>(degA, offA, degE, offE, degR, offR);
    k_relprep<<<NREL, 64, 0, stream>>>(rel_emb, e_attn, r_attn, nrm, attL0, attL1);
    k_place_sliced<<<gT * NSLICE, 256, 0, stream>>>(
        adj_list, adj_list + NTRI, ent_adj, ent_adj + NTRI, rel_adj, rel_adj + NTRI,
        r_index + NTRI, r_val, nrm, offA, offE, offR, curA, curE, curR,
        ePackSc, eColE, eColR);
    k_proxyprep2<<<2 * NPROX, 64, 0, stream>>>(e_proxy, r_proxy, pnT_e, pnT_r);
    k_gateprep2<<<2 * F3, F3, 0, stream>>>(e_gate, r_gate, gTh_e, gTl_e, gTh_r, gTl_r);
    k_pgprep<<<dim3(F3, 2), 64, 0, stream>>>(e_proxy, r_proxy, e_gate, r_gate,
                                             pgTh_e, pgTl_e, prTh_e, prTl_e,
                                             pgTh_r, pgTl_r, prTh_r, prTl_r);

    k_avg2<<<(2 * NNODE) / 4, 256, 0, stream>>>(offE, eColE, ent_emb, offR, eColR, rel_emb,
                                                out_e, out_r);

    int gW = NNODE / 4;
    k_agg2<<<gW, 256, 0, stream>>>(offA, ePackSc, attL0, rel_emb, out_e, out_r, 0);
    k_agg2<<<gW, 256, 0, stream>>>(offA, ePackSc, attL1, rel_emb, out_e, out_r, 1);

    dim3 gS(NNODE / 64, 1, 2);
    k_scores<<<gS, 256, 0, stream>>>(out_e, out_r, pnT_e, pnT_r,
                                     paH_e, paL_e, paH_r, paL_r);
    // XCD-ganged 1D grid: 8 xcd * 12 variants * ceil(313/8)=40 -> 3840 blocks
    k_gate_fused<<<3840, 256, 0, stream>>>(paH_e, paL_e, paH_r, paL_r,
                                           gTh_e, gTl_e, gTh_r, gTl_r,
                                           pgTh_e, pgTl_e, prTh_e, prTl_e,
                                           pgTh_r, pgTl_r, prTh_r, prTl_r,
                                           e_bias, r_bias, out_e, out_r, out);
}